// Round 1
// baseline (5943.866 us; speedup 1.0000x reference)
//
#include <hip/hip_runtime.h>
#include <math.h>

#define B_ 2
#define C_ 8
#define M_ 8
#define NH_ 8
#define F_ 1024
#define W_ 512
#define HD_ 128
#define FW 524288L  // F_*W_

// ---------------- conv 3x3 SAME, NCHW, OIHW weights ----------------
template<int CIN, int ACT>
__global__ __launch_bounds__(256)
void conv3x3_k(const float* __restrict__ in0, int c0,
               const float* __restrict__ in1,
               const float* __restrict__ wgt,
               const float* __restrict__ bias,
               const float* __restrict__ resid,
               float* __restrict__ outp, int Cout)
{
    int w  = blockIdx.x * 16 + threadIdx.x;
    int f  = blockIdx.y * 16 + threadIdx.y;
    int co = blockIdx.z % Cout;
    int b  = blockIdx.z / Cout;
    float acc = bias[co];
    for (int ci = 0; ci < CIN; ++ci) {
        const float* src = (ci < c0)
            ? in0 + ((long)b * c0 + ci) * FW
            : in1 + ((long)b * (CIN - c0) + (ci - c0)) * FW;
        const float* wp = wgt + ((long)co * CIN + ci) * 9;
        #pragma unroll
        for (int df = -1; df <= 1; ++df) {
            int ff = f + df;
            if (ff < 0 || ff >= F_) continue;
            #pragma unroll
            for (int dw = -1; dw <= 1; ++dw) {
                int ww = w + dw;
                if (ww < 0 || ww >= W_) continue;
                acc += src[(long)ff * W_ + ww] * wp[(df + 1) * 3 + (dw + 1)];
            }
        }
    }
    if (ACT == 1) acc = 0.5f * acc * (1.0f + erff(acc * 0.70710678118f));
    long oidx = ((long)b * Cout + co) * FW + (long)f * W_ + w;
    if (resid) acc += resid[oidx];
    outp[oidx] = acc;
}

// ---------------- generic batched tiled fp32 GEMM ----------------
// C[bz] = A[bz%aMod] (M x K, ld=lda) * B[bz] (K x N or N x K if TRANSB)
// EPI==1: C = C*scale + Add[bz]
template<int TRANSB, int EPI>
__global__ __launch_bounds__(256)
void gemm_k(const float* __restrict__ Ab, const float* __restrict__ Bb,
            float* __restrict__ Cb, const float* __restrict__ Addb,
            float scale, int Mdim, int Ndim, int Kdim,
            int lda, int ldb, int ldc,
            long sA, long sB, long sC, long sAdd, int aMod)
{
    int bz = blockIdx.z;
    const float* A = Ab + (long)(bz % aMod) * sA;
    const float* B = Bb + (long)bz * sB;
    float* C = Cb + (long)bz * sC;
    int m0 = blockIdx.y * 64;
    int n0 = blockIdx.x * 64;
    __shared__ float As[16][64];
    __shared__ float Bs[16][64];
    int tid = threadIdx.x;
    int tx = tid & 15, ty = tid >> 4;
    float acc[4][4] = {};
    for (int k0 = 0; k0 < Kdim; k0 += 16) {
        {
            int r  = tid >> 2;
            int kc = (tid & 3) * 4;
            float4 av = *reinterpret_cast<const float4*>(&A[(long)(m0 + r) * lda + k0 + kc]);
            As[kc + 0][r] = av.x; As[kc + 1][r] = av.y;
            As[kc + 2][r] = av.z; As[kc + 3][r] = av.w;
        }
        if (TRANSB) {
            int r  = tid >> 2;
            int kc = (tid & 3) * 4;
            float4 bv = *reinterpret_cast<const float4*>(&B[(long)(n0 + r) * ldb + k0 + kc]);
            Bs[kc + 0][r] = bv.x; Bs[kc + 1][r] = bv.y;
            Bs[kc + 2][r] = bv.z; Bs[kc + 3][r] = bv.w;
        } else {
            int kr = tid >> 4;
            int nc = (tid & 15) * 4;
            float4 bv = *reinterpret_cast<const float4*>(&B[(long)(k0 + kr) * ldb + n0 + nc]);
            Bs[kr][nc + 0] = bv.x; Bs[kr][nc + 1] = bv.y;
            Bs[kr][nc + 2] = bv.z; Bs[kr][nc + 3] = bv.w;
        }
        __syncthreads();
        #pragma unroll
        for (int kk = 0; kk < 16; ++kk) {
            float4 a4 = *reinterpret_cast<const float4*>(&As[kk][ty * 4]);
            float4 b4 = *reinterpret_cast<const float4*>(&Bs[kk][tx * 4]);
            float a0[4] = {a4.x, a4.y, a4.z, a4.w};
            float b0[4] = {b4.x, b4.y, b4.z, b4.w};
            #pragma unroll
            for (int i = 0; i < 4; ++i)
                #pragma unroll
                for (int j = 0; j < 4; ++j)
                    acc[i][j] += a0[i] * b0[j];
        }
        __syncthreads();
    }
    #pragma unroll
    for (int i = 0; i < 4; ++i) {
        int r = m0 + ty * 4 + i;
        #pragma unroll
        for (int j = 0; j < 4; ++j) {
            int c = n0 + tx * 4 + j;
            float v = acc[i][j];
            if (EPI == 1) v = v * scale + Addb[(long)bz * sAdd + (long)r * ldc + c];
            C[(long)r * ldc + c] = v;
        }
    }
}

// ---------------- rope + heads transpose ----------------
// in: (BM, F, W) ; out: (BM, NH, W, HD)  out[bm,n,w,d] = rope(in[bm, n*HD+d, w])
__global__ __launch_bounds__(256)
void rope_t_k(const float* __restrict__ in, float* __restrict__ outp, int doRope)
{
    long idx = (long)blockIdx.x * 256 + threadIdx.x;
    int d = idx & (HD_ - 1);
    int w = (idx >> 7) & (W_ - 1);
    int n = (idx >> 16) & (NH_ - 1);
    long bm = idx >> 19;
    long fin = bm * FW + (long)(n * HD_ + d) * W_ + w;
    float v = in[fin];
    if (doRope) {
        int p = d >> 1;
        float inv = expf(-(float)p * 0.14391156507f);  // ln(10000)/64
        float ang = (float)w * inv;
        float cc, ss;
        sincosf(ang, &cc, &ss);
        float partner = (d & 1) ? in[fin - W_] : in[fin + W_];
        float xr = (d & 1) ? partner : -partner;
        v = v * cc + xr * ss;
    }
    outp[idx] = v;
}

// ---------------- softmax over last dim (512) ----------------
__device__ inline float waveMax(float v) {
    #pragma unroll
    for (int o = 32; o >= 1; o >>= 1) v = fmaxf(v, __shfl_xor(v, o, 64));
    return v;
}
__device__ inline float waveSum(float v) {
    #pragma unroll
    for (int o = 32; o >= 1; o >>= 1) v += __shfl_xor(v, o, 64);
    return v;
}

__global__ __launch_bounds__(256)
void softmax_k(const float* __restrict__ S, float* __restrict__ P)
{
    long row = blockIdx.x;
    const float* s = S + row * 512;
    float* p = P + row * 512;
    int t = threadIdx.x;
    float v0 = s[t], v1 = s[t + 256];
    int wv = t >> 6, ln = t & 63;
    __shared__ float shm[4], shs[4];
    float m = waveMax(fmaxf(v0, v1));
    if (ln == 0) shm[wv] = m;
    __syncthreads();
    float M4 = fmaxf(fmaxf(shm[0], shm[1]), fmaxf(shm[2], shm[3]));
    float e0 = expf(v0 - M4), e1 = expf(v1 - M4);
    float su = waveSum(e0 + e1);
    if (ln == 0) shs[wv] = su;
    __syncthreads();
    float inv = 1.0f / (shs[0] + shs[1] + shs[2] + shs[3]);
    p[t] = e0 * inv;
    p[t + 256] = e1 * inv;
}

// ---------------- attention output untranspose ----------------
// a: (BM, NH, W, HD) -> af: (BM, F, W)
__global__ __launch_bounds__(256)
void afeat_k(const float* __restrict__ a, float* __restrict__ af)
{
    long idx = (long)blockIdx.x * 256 + threadIdx.x;
    int w = idx & (W_ - 1);
    int f = (idx >> 9) & (F_ - 1);
    long bm = idx >> 19;
    int n = f >> 7, d = f & (HD_ - 1);
    af[idx] = a[((bm * NH_ + n) * W_ + w) * HD_ + d];
}

// ---------------- depthwise o_dw mix: out[b,d] = sum_c t[b,c]*dw[d,c] ----------------
__global__ __launch_bounds__(256)
void odw_k(const float* __restrict__ t, const float* __restrict__ dw, float* __restrict__ o)
{
    long idx = (long)blockIdx.x * 256 + threadIdx.x;
    long fw = idx & (FW - 1);
    int dch = (idx >> 19) & (M_ - 1);
    long b = idx >> 22;
    float acc = 0.f;
    #pragma unroll
    for (int c = 0; c < M_; ++c)
        acc += t[(b * M_ + c) * FW + fw] * dw[dch * M_ + c];
    o[idx] = acc;
}

// ---------------- multichannel layernorm over F axis ----------------
__global__ __launch_bounds__(256)
void mcln_k(const float* __restrict__ in, const float* __restrict__ gam,
            const float* __restrict__ bet, float* __restrict__ o1, float* __restrict__ o2)
{
    int wi = threadIdx.x & 31, fg = threadIdx.x >> 5;
    int w0 = blockIdx.x * 32;
    int c = blockIdx.y, b = blockIdx.z;
    long base = ((long)b * C_ + c) * FW + w0 + wi;
    float s = 0.f, q = 0.f;
    for (int f = fg; f < F_; f += 8) {
        float v = in[base + (long)f * W_];
        s += v; q += v * v;
    }
    __shared__ float rs[8][33], rq[8][33];
    __shared__ float mu_s[32], inv_s[32];
    rs[fg][wi] = s; rq[fg][wi] = q;
    __syncthreads();
    if (fg == 0) {
        float ts = 0.f, tq = 0.f;
        for (int g = 0; g < 8; ++g) { ts += rs[g][wi]; tq += rq[g][wi]; }
        float mu = ts * (1.0f / F_);
        float var = tq * (1.0f / F_) - mu * mu;
        mu_s[wi] = mu;
        inv_s[wi] = rsqrtf(var + 1e-5f);
    }
    __syncthreads();
    float mu = mu_s[wi], inv = inv_s[wi];
    for (int f = fg; f < F_; f += 8) {
        float v = in[base + (long)f * W_];
        float r = (v - mu) * inv * gam[c * F_ + f] + bet[c * F_ + f];
        long oi = base + (long)f * W_;
        o1[oi] = r;
        if (o2) o2[oi] = r;
    }
}

extern "C" void kernel_launch(void* const* d_in, const int* in_sizes, int n_in,
                              void* d_out, int out_size, void* d_ws, size_t ws_size,
                              hipStream_t stream) {
    (void)in_sizes; (void)n_in; (void)out_size; (void)ws_size;
    const float* x        = (const float*)d_in[0];
    const float* prev_qk  = (const float*)d_in[1];
    const float* qconv_w  = (const float*)d_in[2];
    const float* qconv_b  = (const float*)d_in[3];
    const float* q_pw     = (const float*)d_in[4];
    const float* kconv_w  = (const float*)d_in[5];
    const float* kconv_b  = (const float*)d_in[6];
    const float* k_pw     = (const float*)d_in[7];
    const float* vconv_w  = (const float*)d_in[8];
    const float* vconv_b  = (const float*)d_in[9];
    const float* v_pw     = (const float*)d_in[10];
    const float* o_pw     = (const float*)d_in[11];
    const float* o_dw     = (const float*)d_in[12];
    const float* oproj_w  = (const float*)d_in[13];
    const float* oproj_b  = (const float*)d_in[14];
    const float* n1_w     = (const float*)d_in[15];
    const float* n1_b     = (const float*)d_in[16];
    const float* c1_w     = (const float*)d_in[17];
    const float* c1_b     = (const float*)d_in[18];
    const float* c2_w     = (const float*)d_in[19];
    const float* c2_b     = (const float*)d_in[20];
    const float* n2_w     = (const float*)d_in[21];
    const float* n2_b     = (const float*)d_in[22];

    float* out    = (float*)d_out;
    float* qk_out = out + 16777216L;  // after two copies of `out`
    float* ws = (float*)d_ws;
    float* S0 = ws;               // 8.39M: conv scratch, later a_feat
    float* S1 = ws + 8388608L;    // ql, later a, later t
    float* S2 = ws + 16777216L;   // kl, later a2
    float* S3 = ws + 25165824L;   // vl, later pre1
    float* S4 = ws + 33554432L;   // q (roped)
    float* S5 = ws + 41943040L;   // k (roped), later hid
    float* S6 = ws + 50331648L;   // v, later pre2
    float* S7 = ws + 58720256L;   // 33.5M: P, later c1out

    dim3 cgrid(W_ / 16, F_ / 16, B_ * M_);
    dim3 cblk(16, 16);

    // Q path
    conv3x3_k<8, 0><<<cgrid, cblk, 0, stream>>>(x, 8, nullptr, qconv_w, qconv_b, nullptr, S0, M_);
    gemm_k<0, 0><<<dim3(W_ / 64, F_ / 64, B_ * M_), 256, 0, stream>>>(
        q_pw, S0, S1, nullptr, 1.f, F_, W_, F_, F_, W_, W_, (long)F_ * F_, FW, FW, 0L, M_);
    // K path
    conv3x3_k<8, 0><<<cgrid, cblk, 0, stream>>>(x, 8, nullptr, kconv_w, kconv_b, nullptr, S0, M_);
    gemm_k<0, 0><<<dim3(W_ / 64, F_ / 64, B_ * M_), 256, 0, stream>>>(
        k_pw, S0, S2, nullptr, 1.f, F_, W_, F_, F_, W_, W_, (long)F_ * F_, FW, FW, 0L, M_);
    // V path
    conv3x3_k<8, 0><<<cgrid, cblk, 0, stream>>>(x, 8, nullptr, vconv_w, vconv_b, nullptr, S0, M_);
    gemm_k<0, 0><<<dim3(W_ / 64, F_ / 64, B_ * M_), 256, 0, stream>>>(
        v_pw, S0, S3, nullptr, 1.f, F_, W_, F_, F_, W_, W_, (long)F_ * F_, FW, FW, 0L, M_);

    // heads + rope
    rope_t_k<<<32768, 256, 0, stream>>>(S1, S4, 1);
    rope_t_k<<<32768, 256, 0, stream>>>(S2, S5, 1);
    rope_t_k<<<32768, 256, 0, stream>>>(S3, S6, 0);

    // qk = Q K^T / 32 + prev_qk  (written directly to output)
    gemm_k<1, 1><<<dim3(8, 8, 128), 256, 0, stream>>>(
        S4, S5, qk_out, prev_qk, 0.03125f, 512, 512, 128, 128, 128, 512,
        (long)W_ * HD_, (long)W_ * HD_, (long)W_ * W_, (long)W_ * W_, 128);

    // softmax
    softmax_k<<<65536, 256, 0, stream>>>(qk_out, S7);

    // a = P V
    gemm_k<0, 0><<<dim3(2, 8, 128), 256, 0, stream>>>(
        S7, S6, S1, nullptr, 1.f, 512, 128, 512, 512, 128, 128,
        (long)W_ * W_, (long)W_ * HD_, (long)W_ * HD_, 0L, 128);

    // back to (B,M,F,W)
    afeat_k<<<32768, 256, 0, stream>>>(S1, S0);

    // o linear + depthwise mix
    gemm_k<0, 0><<<dim3(W_ / 64, F_ / 64, B_ * M_), 256, 0, stream>>>(
        o_pw, S0, S1, nullptr, 1.f, F_, W_, F_, F_, W_, W_, (long)F_ * F_, FW, FW, 0L, M_);
    odw_k<<<32768, 256, 0, stream>>>(S1, o_dw, S2);

    // oproj conv over concat(x, a2) + x residual -> pre1
    conv3x3_k<16, 0><<<dim3(W_ / 16, F_ / 16, B_ * C_), cblk, 0, stream>>>(
        x, 8, S2, oproj_w, oproj_b, x, S3, C_);

    // hid = mcln(pre1)
    mcln_k<<<dim3(16, 8, 2), 256, 0, stream>>>(S3, n1_w, n1_b, S5, nullptr);

    // c1 conv + gelu
    conv3x3_k<8, 1><<<dim3(W_ / 16, F_ / 16, B_ * 32), cblk, 0, stream>>>(
        S5, 8, nullptr, c1_w, c1_b, nullptr, S7, 32);
    // c2 conv + hid residual -> pre2
    conv3x3_k<32, 0><<<dim3(W_ / 16, F_ / 16, B_ * C_), cblk, 0, stream>>>(
        S7, 32, nullptr, c2_w, c2_b, S5, S6, C_);

    // out = mcln(pre2), written to both output copies
    mcln_k<<<dim3(16, 8, 2), 256, 0, stream>>>(S6, n2_w, n2_b, out, out + 8388608L);
}

// Round 2
// 2312.058 us; speedup vs baseline: 2.5708x; 2.5708x over previous
//
#include <hip/hip_runtime.h>
#include <math.h>

#define B_ 2
#define C_ 8
#define M_ 8
#define NH_ 8
#define F_ 1024
#define W_ 512
#define HD_ 128
#define FW 524288L  // F_*W_

// ---------------- conv 3x3 SAME via LDS-staged spatial tile ----------------
// Block: 256 threads = 32(w) x 8(f) spatial tile; computes ALL Cout channels.
// Input halo tile (CIN x 10 x 34) staged in LDS once.
template<int CIN, int COUT, int ACT>
__global__ __launch_bounds__(256)
void conv3x3_lds_k(const float* __restrict__ in0, int c0,
                   const float* __restrict__ in1,
                   const float* __restrict__ wgt,
                   const float* __restrict__ bias,
                   const float* __restrict__ resid,
                   float* __restrict__ outp)
{
    __shared__ float s_in[CIN][10][34];
    const int tid = threadIdx.x;
    const int w0 = blockIdx.x * 32;
    const int f0 = blockIdx.y * 8;
    const int b  = blockIdx.z;

    // ---- stage input tile (zero-padded halo) ----
    for (int idx = tid; idx < CIN * 340; idx += 256) {
        int ci  = idx / 340;
        int rem = idx - ci * 340;
        int r   = rem / 34;
        int cc  = rem - r * 34;
        int f = f0 + r - 1;
        int w = w0 + cc - 1;
        float v = 0.f;
        if (f >= 0 && f < F_ && w >= 0 && w < W_) {
            const float* src = (ci < c0)
                ? in0 + ((long)b * c0 + ci) * FW
                : in1 + ((long)b * (CIN - c0) + (ci - c0)) * FW;
            v = src[(long)f * W_ + w];
        }
        s_in[ci][r][cc] = v;
    }
    __syncthreads();

    const int tx = tid & 31;        // w within tile
    const int ty = tid >> 5;        // f within tile

    float acc[COUT];
    #pragma unroll
    for (int co = 0; co < COUT; ++co) acc[co] = bias[co];

    for (int ci = 0; ci < CIN; ++ci) {
        #pragma unroll
        for (int df = 0; df < 3; ++df) {
            #pragma unroll
            for (int dw = 0; dw < 3; ++dw) {
                float v = s_in[ci][ty + df][tx + dw];
                #pragma unroll
                for (int co = 0; co < COUT; ++co)
                    acc[co] += v * wgt[((co * CIN + ci) * 9) + df * 3 + dw];
            }
        }
    }

    const long pix = (long)(f0 + ty) * W_ + (w0 + tx);
    #pragma unroll
    for (int co = 0; co < COUT; ++co) {
        float v = acc[co];
        if (ACT == 1) v = 0.5f * v * (1.0f + erff(v * 0.70710678118f));
        long oidx = ((long)b * COUT + co) * FW + pix;
        if (resid) v += resid[oidx];
        outp[oidx] = v;
    }
}

// ---------------- generic batched tiled fp32 GEMM ----------------
// C[bz] = A[bz%aMod] (M x K, ld=lda) * B[bz] (K x N or N x K if TRANSB)
// EPI==1: C = C*scale + Add[bz]
template<int TRANSB, int EPI>
__global__ __launch_bounds__(256)
void gemm_k(const float* __restrict__ Ab, const float* __restrict__ Bb,
            float* __restrict__ Cb, const float* __restrict__ Addb,
            float scale, int Mdim, int Ndim, int Kdim,
            int lda, int ldb, int ldc,
            long sA, long sB, long sC, long sAdd, int aMod)
{
    int bz = blockIdx.z;
    const float* A = Ab + (long)(bz % aMod) * sA;
    const float* B = Bb + (long)bz * sB;
    float* C = Cb + (long)bz * sC;
    int m0 = blockIdx.y * 64;
    int n0 = blockIdx.x * 64;
    __shared__ float As[16][64];
    __shared__ float Bs[16][64];
    int tid = threadIdx.x;
    int tx = tid & 15, ty = tid >> 4;
    float acc[4][4] = {};
    for (int k0 = 0; k0 < Kdim; k0 += 16) {
        {
            int r  = tid >> 2;
            int kc = (tid & 3) * 4;
            float4 av = *reinterpret_cast<const float4*>(&A[(long)(m0 + r) * lda + k0 + kc]);
            As[kc + 0][r] = av.x; As[kc + 1][r] = av.y;
            As[kc + 2][r] = av.z; As[kc + 3][r] = av.w;
        }
        if (TRANSB) {
            int r  = tid >> 2;
            int kc = (tid & 3) * 4;
            float4 bv = *reinterpret_cast<const float4*>(&B[(long)(n0 + r) * ldb + k0 + kc]);
            Bs[kc + 0][r] = bv.x; Bs[kc + 1][r] = bv.y;
            Bs[kc + 2][r] = bv.z; Bs[kc + 3][r] = bv.w;
        } else {
            int kr = tid >> 4;
            int nc = (tid & 15) * 4;
            float4 bv = *reinterpret_cast<const float4*>(&B[(long)(k0 + kr) * ldb + n0 + nc]);
            Bs[kr][nc + 0] = bv.x; Bs[kr][nc + 1] = bv.y;
            Bs[kr][nc + 2] = bv.z; Bs[kr][nc + 3] = bv.w;
        }
        __syncthreads();
        #pragma unroll
        for (int kk = 0; kk < 16; ++kk) {
            float4 a4 = *reinterpret_cast<const float4*>(&As[kk][ty * 4]);
            float4 b4 = *reinterpret_cast<const float4*>(&Bs[kk][tx * 4]);
            float a0[4] = {a4.x, a4.y, a4.z, a4.w};
            float b0[4] = {b4.x, b4.y, b4.z, b4.w};
            #pragma unroll
            for (int i = 0; i < 4; ++i)
                #pragma unroll
                for (int j = 0; j < 4; ++j)
                    acc[i][j] += a0[i] * b0[j];
        }
        __syncthreads();
    }
    #pragma unroll
    for (int i = 0; i < 4; ++i) {
        int r = m0 + ty * 4 + i;
        #pragma unroll
        for (int j = 0; j < 4; ++j) {
            int c = n0 + tx * 4 + j;
            float v = acc[i][j];
            if (EPI == 1) v = v * scale + Addb[(long)bz * sAdd + (long)r * ldc + c];
            C[(long)r * ldc + c] = v;
        }
    }
}

// ---------------- rope + heads transpose ----------------
// in: (BM, F, W) ; out: (BM, NH, W, HD)  out[bm,n,w,d] = rope(in[bm, n*HD+d, w])
__global__ __launch_bounds__(256)
void rope_t_k(const float* __restrict__ in, float* __restrict__ outp, int doRope)
{
    long idx = (long)blockIdx.x * 256 + threadIdx.x;
    int d = idx & (HD_ - 1);
    int w = (idx >> 7) & (W_ - 1);
    int n = (idx >> 16) & (NH_ - 1);
    long bm = idx >> 19;
    long fin = bm * FW + (long)(n * HD_ + d) * W_ + w;
    float v = in[fin];
    if (doRope) {
        int p = d >> 1;
        float inv = expf(-(float)p * 0.14391156507f);  // ln(10000)/64
        float ang = (float)w * inv;
        float cc, ss;
        sincosf(ang, &cc, &ss);
        float partner = (d & 1) ? in[fin - W_] : in[fin + W_];
        float xr = (d & 1) ? partner : -partner;
        v = v * cc + xr * ss;
    }
    outp[idx] = v;
}

// ---------------- softmax over last dim (512) ----------------
__device__ inline float waveMax(float v) {
    #pragma unroll
    for (int o = 32; o >= 1; o >>= 1) v = fmaxf(v, __shfl_xor(v, o, 64));
    return v;
}
__device__ inline float waveSum(float v) {
    #pragma unroll
    for (int o = 32; o >= 1; o >>= 1) v += __shfl_xor(v, o, 64);
    return v;
}

__global__ __launch_bounds__(256)
void softmax_k(const float* __restrict__ S, float* __restrict__ P)
{
    long row = blockIdx.x;
    const float* s = S + row * 512;
    float* p = P + row * 512;
    int t = threadIdx.x;
    float v0 = s[t], v1 = s[t + 256];
    int wv = t >> 6, ln = t & 63;
    __shared__ float shm[4], shs[4];
    float m = waveMax(fmaxf(v0, v1));
    if (ln == 0) shm[wv] = m;
    __syncthreads();
    float M4 = fmaxf(fmaxf(shm[0], shm[1]), fmaxf(shm[2], shm[3]));
    float e0 = expf(v0 - M4), e1 = expf(v1 - M4);
    float su = waveSum(e0 + e1);
    if (ln == 0) shs[wv] = su;
    __syncthreads();
    float inv = 1.0f / (shs[0] + shs[1] + shs[2] + shs[3]);
    p[t] = e0 * inv;
    p[t + 256] = e1 * inv;
}

// ---------------- attention output untranspose ----------------
// a: (BM, NH, W, HD) -> af: (BM, F, W)
__global__ __launch_bounds__(256)
void afeat_k(const float* __restrict__ a, float* __restrict__ af)
{
    long idx = (long)blockIdx.x * 256 + threadIdx.x;
    int w = idx & (W_ - 1);
    int f = (idx >> 9) & (F_ - 1);
    long bm = idx >> 19;
    int n = f >> 7, d = f & (HD_ - 1);
    af[idx] = a[((bm * NH_ + n) * W_ + w) * HD_ + d];
}

// ---------------- depthwise o_dw mix: out[b,d] = sum_c t[b,c]*dw[d,c] ----------------
__global__ __launch_bounds__(256)
void odw_k(const float* __restrict__ t, const float* __restrict__ dw, float* __restrict__ o)
{
    long idx = (long)blockIdx.x * 256 + threadIdx.x;
    long fw = idx & (FW - 1);
    int dch = (idx >> 19) & (M_ - 1);
    long b = idx >> 22;
    float acc = 0.f;
    #pragma unroll
    for (int c = 0; c < M_; ++c)
        acc += t[(b * M_ + c) * FW + fw] * dw[dch * M_ + c];
    o[idx] = acc;
}

// ---------------- multichannel layernorm over F axis ----------------
__global__ __launch_bounds__(256)
void mcln_k(const float* __restrict__ in, const float* __restrict__ gam,
            const float* __restrict__ bet, float* __restrict__ o1, float* __restrict__ o2)
{
    int wi = threadIdx.x & 31, fg = threadIdx.x >> 5;
    int w0 = blockIdx.x * 32;
    int c = blockIdx.y, b = blockIdx.z;
    long base = ((long)b * C_ + c) * FW + w0 + wi;
    float s = 0.f, q = 0.f;
    for (int f = fg; f < F_; f += 8) {
        float v = in[base + (long)f * W_];
        s += v; q += v * v;
    }
    __shared__ float rs[8][33], rq[8][33];
    __shared__ float mu_s[32], inv_s[32];
    rs[fg][wi] = s; rq[fg][wi] = q;
    __syncthreads();
    if (fg == 0) {
        float ts = 0.f, tq = 0.f;
        for (int g = 0; g < 8; ++g) { ts += rs[g][wi]; tq += rq[g][wi]; }
        float mu = ts * (1.0f / F_);
        float var = tq * (1.0f / F_) - mu * mu;
        mu_s[wi] = mu;
        inv_s[wi] = rsqrtf(var + 1e-5f);
    }
    __syncthreads();
    float mu = mu_s[wi], inv = inv_s[wi];
    for (int f = fg; f < F_; f += 8) {
        float v = in[base + (long)f * W_];
        float r = (v - mu) * inv * gam[c * F_ + f] + bet[c * F_ + f];
        long oi = base + (long)f * W_;
        o1[oi] = r;
        if (o2) o2[oi] = r;
    }
}

extern "C" void kernel_launch(void* const* d_in, const int* in_sizes, int n_in,
                              void* d_out, int out_size, void* d_ws, size_t ws_size,
                              hipStream_t stream) {
    (void)in_sizes; (void)n_in; (void)out_size; (void)ws_size;
    const float* x        = (const float*)d_in[0];
    const float* prev_qk  = (const float*)d_in[1];
    const float* qconv_w  = (const float*)d_in[2];
    const float* qconv_b  = (const float*)d_in[3];
    const float* q_pw     = (const float*)d_in[4];
    const float* kconv_w  = (const float*)d_in[5];
    const float* kconv_b  = (const float*)d_in[6];
    const float* k_pw     = (const float*)d_in[7];
    const float* vconv_w  = (const float*)d_in[8];
    const float* vconv_b  = (const float*)d_in[9];
    const float* v_pw     = (const float*)d_in[10];
    const float* o_pw     = (const float*)d_in[11];
    const float* o_dw     = (const float*)d_in[12];
    const float* oproj_w  = (const float*)d_in[13];
    const float* oproj_b  = (const float*)d_in[14];
    const float* n1_w     = (const float*)d_in[15];
    const float* n1_b     = (const float*)d_in[16];
    const float* c1_w     = (const float*)d_in[17];
    const float* c1_b     = (const float*)d_in[18];
    const float* c2_w     = (const float*)d_in[19];
    const float* c2_b     = (const float*)d_in[20];
    const float* n2_w     = (const float*)d_in[21];
    const float* n2_b     = (const float*)d_in[22];

    float* out    = (float*)d_out;
    float* qk_out = out + 16777216L;  // after two copies of `out`
    float* ws = (float*)d_ws;
    float* S0 = ws;               // 8.39M: conv scratch, later a_feat
    float* S1 = ws + 8388608L;    // ql, later a, later t
    float* S2 = ws + 16777216L;   // kl, later a2
    float* S3 = ws + 25165824L;   // vl, later pre1
    float* S4 = ws + 33554432L;   // q (roped)
    float* S5 = ws + 41943040L;   // k (roped), later hid
    float* S6 = ws + 50331648L;   // v, later pre2
    float* S7 = ws + 58720256L;   // 33.5M: P, later c1out

    dim3 cgrid(W_ / 32, F_ / 8, B_);  // 16 x 128 x 2

    // Q path
    conv3x3_lds_k<8, 8, 0><<<cgrid, 256, 0, stream>>>(x, 8, nullptr, qconv_w, qconv_b, nullptr, S0);
    gemm_k<0, 0><<<dim3(W_ / 64, F_ / 64, B_ * M_), 256, 0, stream>>>(
        q_pw, S0, S1, nullptr, 1.f, F_, W_, F_, F_, W_, W_, (long)F_ * F_, FW, FW, 0L, M_);
    // K path
    conv3x3_lds_k<8, 8, 0><<<cgrid, 256, 0, stream>>>(x, 8, nullptr, kconv_w, kconv_b, nullptr, S0);
    gemm_k<0, 0><<<dim3(W_ / 64, F_ / 64, B_ * M_), 256, 0, stream>>>(
        k_pw, S0, S2, nullptr, 1.f, F_, W_, F_, F_, W_, W_, (long)F_ * F_, FW, FW, 0L, M_);
    // V path
    conv3x3_lds_k<8, 8, 0><<<cgrid, 256, 0, stream>>>(x, 8, nullptr, vconv_w, vconv_b, nullptr, S0);
    gemm_k<0, 0><<<dim3(W_ / 64, F_ / 64, B_ * M_), 256, 0, stream>>>(
        v_pw, S0, S3, nullptr, 1.f, F_, W_, F_, F_, W_, W_, (long)F_ * F_, FW, FW, 0L, M_);

    // heads + rope
    rope_t_k<<<32768, 256, 0, stream>>>(S1, S4, 1);
    rope_t_k<<<32768, 256, 0, stream>>>(S2, S5, 1);
    rope_t_k<<<32768, 256, 0, stream>>>(S3, S6, 0);

    // qk = Q K^T / 32 + prev_qk  (written directly to output)
    gemm_k<1, 1><<<dim3(8, 8, 128), 256, 0, stream>>>(
        S4, S5, qk_out, prev_qk, 0.03125f, 512, 512, 128, 128, 128, 512,
        (long)W_ * HD_, (long)W_ * HD_, (long)W_ * W_, (long)W_ * W_, 128);

    // softmax
    softmax_k<<<65536, 256, 0, stream>>>(qk_out, S7);

    // a = P V
    gemm_k<0, 0><<<dim3(2, 8, 128), 256, 0, stream>>>(
        S7, S6, S1, nullptr, 1.f, 512, 128, 512, 512, 128, 128,
        (long)W_ * W_, (long)W_ * HD_, (long)W_ * HD_, 0L, 128);

    // back to (B,M,F,W)
    afeat_k<<<32768, 256, 0, stream>>>(S1, S0);

    // o linear + depthwise mix
    gemm_k<0, 0><<<dim3(W_ / 64, F_ / 64, B_ * M_), 256, 0, stream>>>(
        o_pw, S0, S1, nullptr, 1.f, F_, W_, F_, F_, W_, W_, (long)F_ * F_, FW, FW, 0L, M_);
    odw_k<<<32768, 256, 0, stream>>>(S1, o_dw, S2);

    // oproj conv over concat(x, a2) + x residual -> pre1
    conv3x3_lds_k<16, 8, 0><<<cgrid, 256, 0, stream>>>(
        x, 8, S2, oproj_w, oproj_b, x, S3);

    // hid = mcln(pre1)
    mcln_k<<<dim3(16, 8, 2), 256, 0, stream>>>(S3, n1_w, n1_b, S5, nullptr);

    // c1 conv + gelu
    conv3x3_lds_k<8, 32, 1><<<cgrid, 256, 0, stream>>>(
        S5, 8, nullptr, c1_w, c1_b, nullptr, S7);
    // c2 conv + hid residual -> pre2
    conv3x3_lds_k<32, 8, 0><<<cgrid, 256, 0, stream>>>(
        S7, 32, nullptr, c2_w, c2_b, S5, S6);

    // out = mcln(pre2), written to both output copies
    mcln_k<<<dim3(16, 8, 2), 256, 0, stream>>>(S6, n2_w, n2_b, out, out + 8388608L);
}

// Round 3
// 1359.300 us; speedup vs baseline: 4.3727x; 1.7009x over previous
//
#include <hip/hip_runtime.h>
#include <math.h>

#define B_ 2
#define C_ 8
#define M_ 8
#define NH_ 8
#define F_ 1024
#define W_ 512
#define HD_ 128
#define FW 524288L  // F_*W_

typedef __bf16 bf16_t;
typedef __bf16 bf16x8 __attribute__((ext_vector_type(8)));
typedef __bf16 bf16x4 __attribute__((ext_vector_type(4)));
typedef float f32x4 __attribute__((ext_vector_type(4)));

__device__ __forceinline__ void gload16(const void* g, void* l) {
    __builtin_amdgcn_global_load_lds(
        (const __attribute__((address_space(1))) unsigned int*)g,
        (__attribute__((address_space(3))) unsigned int*)l,
        16, 0, 0);
}

// ---------------- conv 3x3 SAME via LDS-staged spatial tile ----------------
template<typename TIN, int CIN, int COUT, int ACT, int OUTBF>
__global__ __launch_bounds__(256)
void conv3x3_lds_k(const TIN* __restrict__ in0, int c0,
                   const float* __restrict__ in1,
                   const float* __restrict__ wgt,
                   const float* __restrict__ bias,
                   const float* __restrict__ resid,
                   void* __restrict__ outp)
{
    __shared__ float s_in[CIN][10][34];
    const int tid = threadIdx.x;
    const int w0 = blockIdx.x * 32;
    const int f0 = blockIdx.y * 8;
    const int b  = blockIdx.z;

    for (int idx = tid; idx < CIN * 340; idx += 256) {
        int ci  = idx / 340;
        int rem = idx - ci * 340;
        int r   = rem / 34;
        int cc  = rem - r * 34;
        int f = f0 + r - 1;
        int w = w0 + cc - 1;
        float v = 0.f;
        if (f >= 0 && f < F_ && w >= 0 && w < W_) {
            if (ci < c0)
                v = (float)in0[((long)b * c0 + ci) * FW + (long)f * W_ + w];
            else
                v = in1[((long)b * (CIN - c0) + (ci - c0)) * FW + (long)f * W_ + w];
        }
        s_in[ci][r][cc] = v;
    }
    __syncthreads();

    const int tx = tid & 31;
    const int ty = tid >> 5;

    float acc[COUT];
    #pragma unroll
    for (int co = 0; co < COUT; ++co) acc[co] = bias[co];

    for (int ci = 0; ci < CIN; ++ci) {
        #pragma unroll
        for (int df = 0; df < 3; ++df) {
            #pragma unroll
            for (int dw = 0; dw < 3; ++dw) {
                float v = s_in[ci][ty + df][tx + dw];
                #pragma unroll
                for (int co = 0; co < COUT; ++co)
                    acc[co] += v * wgt[((co * CIN + ci) * 9) + df * 3 + dw];
            }
        }
    }

    const long pix = (long)(f0 + ty) * W_ + (w0 + tx);
    #pragma unroll
    for (int co = 0; co < COUT; ++co) {
        float v = acc[co];
        if (ACT == 1) v = 0.5f * v * (1.0f + erff(v * 0.70710678118f));
        long oidx = ((long)b * COUT + co) * FW + pix;
        if (resid) v += resid[oidx];
        if (OUTBF) ((bf16_t*)outp)[oidx] = (bf16_t)v;
        else       ((float*)outp)[oidx]  = v;
    }
}

// ---------------- bf16 MFMA GEMM: C = A(MxK) * B^T-stored(NxK) ----------------
// A row-major [M][K] ld=lda ; B stored as B^T row-major [N][K] ld=ldb.
// Tile 128x128, BK=32, 4 waves, each wave 64x64 (4x4 frags of 16x16x32).
// EPI==1: C = C*scale + Add[z].  OUTBF: store bf16.
template<int EPI, int OUTBF>
__global__ __launch_bounds__(256)
void gemm_mfma_k(const bf16_t* __restrict__ Ab, const bf16_t* __restrict__ Bb,
                 void* __restrict__ Cb, const float* __restrict__ Addb,
                 float scale, int Kdim, int lda, int ldb, int ldc,
                 long sA, long sB, long sC_hi, long sC_lo, int zdivC,
                 long sAdd, int aMod)
{
    __shared__ bf16_t sAt[4096];   // [128][32]
    __shared__ bf16_t sBt[4096];   // [128][32]

    const int z = blockIdx.z;
    const bf16_t* A = Ab + (long)(z % aMod) * sA;
    const bf16_t* B = Bb + (long)z * sB;
    const int m0 = blockIdx.y * 128;
    const int n0 = blockIdx.x * 128;
    const int tid = threadIdx.x;
    const int lane = tid & 63, wid = tid >> 6;
    const int wr = (wid >> 1) * 64, wc = (wid & 1) * 64;
    const int l15 = lane & 15, l4 = lane >> 4;

    f32x4 acc[4][4];
    #pragma unroll
    for (int m = 0; m < 4; ++m)
        #pragma unroll
        for (int n = 0; n < 4; ++n)
            acc[m][n] = (f32x4){0.f, 0.f, 0.f, 0.f};

    const int srow = tid >> 2;
    const int scol = (tid & 3) * 8;
    const long gA0 = (long)(m0 + srow) * lda + scol;
    const long gA1 = (long)(m0 + 64 + srow) * lda + scol;
    const long gB0 = (long)(n0 + srow) * ldb + scol;
    const long gB1 = (long)(n0 + 64 + srow) * ldb + scol;
    bf16_t* lA = sAt + wid * 512;   // wave-uniform LDS base
    bf16_t* lB = sBt + wid * 512;

    for (int k0 = 0; k0 < Kdim; k0 += 32) {
        __syncthreads();
        gload16(A + gA0 + k0, lA);
        gload16(A + gA1 + k0, lA + 2048);
        gload16(B + gB0 + k0, lB);
        gload16(B + gB1 + k0, lB + 2048);
        __syncthreads();   // drains vmcnt(0) before barrier

        bf16x8 af[4], bfr[4];
        #pragma unroll
        for (int m = 0; m < 4; ++m)
            af[m] = *(const bf16x8*)&sAt[(wr + m * 16 + l15) * 32 + l4 * 8];
        #pragma unroll
        for (int n = 0; n < 4; ++n)
            bfr[n] = *(const bf16x8*)&sBt[(wc + n * 16 + l15) * 32 + l4 * 8];
        #pragma unroll
        for (int m = 0; m < 4; ++m)
            #pragma unroll
            for (int n = 0; n < 4; ++n)
                acc[m][n] = __builtin_amdgcn_mfma_f32_16x16x32_bf16(
                    af[m], bfr[n], acc[m][n], 0, 0, 0);
    }

    const long zc = (long)(z / zdivC) * sC_hi + (long)(z % zdivC) * sC_lo;
    #pragma unroll
    for (int m = 0; m < 4; ++m) {
        #pragma unroll
        for (int n = 0; n < 4; ++n) {
            #pragma unroll
            for (int r = 0; r < 4; ++r) {
                int row = m0 + wr + m * 16 + l4 * 4 + r;
                int col = n0 + wc + n * 16 + l15;
                float v = acc[m][n][r];
                if (EPI) v = v * scale + Addb[(long)z * sAdd + (long)row * ldc + col];
                long cidx = zc + (long)row * ldc + col;
                if (OUTBF) ((bf16_t*)Cb)[cidx] = (bf16_t)v;
                else       ((float*)Cb)[cidx]  = v;
            }
        }
    }
}

// ---------------- transpose+cvt: fp32 [F][W] -> bf16 [W][F] per slice ----------------
__global__ __launch_bounds__(256)
void tcvt_k(const float* __restrict__ in, bf16_t* __restrict__ outp)
{
    __shared__ float tile[32][33];
    const int w0 = blockIdx.x * 32, f0 = blockIdx.y * 32;
    const long base = (long)blockIdx.z * FW;
    const int tx = threadIdx.x & 31, ty = threadIdx.x >> 5;
    #pragma unroll
    for (int i = 0; i < 4; ++i)
        tile[ty + i * 8][tx] = in[base + (long)(f0 + ty + i * 8) * W_ + w0 + tx];
    __syncthreads();
    #pragma unroll
    for (int i = 0; i < 4; ++i)
        outp[base + (long)(w0 + ty + i * 8) * F_ + f0 + tx] = (bf16_t)tile[tx][ty + i * 8];
}

// ---------------- flat fp32 -> bf16 ----------------
__global__ __launch_bounds__(256)
void cvt_k(const float* __restrict__ in, bf16_t* __restrict__ o, int n4)
{
    int i = blockIdx.x * 256 + threadIdx.x;
    if (i < n4) {
        float4 v = ((const float4*)in)[i];
        bf16x4 r = { (bf16_t)v.x, (bf16_t)v.y, (bf16_t)v.z, (bf16_t)v.w };
        *(bf16x4*)&o[(long)i * 4] = r;
    }
}

// ---------------- rope + heads transpose, bf16 out ----------------
__global__ __launch_bounds__(256)
void rope_t_k(const float* __restrict__ in, bf16_t* __restrict__ outp)
{
    long idx = (long)blockIdx.x * 256 + threadIdx.x;
    int d = idx & (HD_ - 1);
    int w = (idx >> 7) & (W_ - 1);
    int n = (idx >> 16) & (NH_ - 1);
    long bm = idx >> 19;
    long fin = bm * FW + (long)(n * HD_ + d) * W_ + w;
    float v = in[fin];
    int p = d >> 1;
    float inv = expf(-(float)p * 0.14391156507f);  // ln(10000)/64
    float ang = (float)w * inv;
    float cc, ss;
    sincosf(ang, &cc, &ss);
    float partner = (d & 1) ? in[fin - W_] : in[fin + W_];
    float xr = (d & 1) ? partner : -partner;
    v = v * cc + xr * ss;
    outp[idx] = (bf16_t)v;
}

// ---------------- softmax over last dim (512), bf16 out ----------------
__device__ inline float waveMax(float v) {
    #pragma unroll
    for (int o = 32; o >= 1; o >>= 1) v = fmaxf(v, __shfl_xor(v, o, 64));
    return v;
}
__device__ inline float waveSum(float v) {
    #pragma unroll
    for (int o = 32; o >= 1; o >>= 1) v += __shfl_xor(v, o, 64);
    return v;
}

__global__ __launch_bounds__(256)
void softmax_k(const float* __restrict__ S, bf16_t* __restrict__ P)
{
    long row = blockIdx.x;
    const float* s = S + row * 512;
    bf16_t* p = P + row * 512;
    int t = threadIdx.x;
    float v0 = s[t], v1 = s[t + 256];
    int wv = t >> 6, ln = t & 63;
    __shared__ float shm[4], shs[4];
    float m = waveMax(fmaxf(v0, v1));
    if (ln == 0) shm[wv] = m;
    __syncthreads();
    float M4 = fmaxf(fmaxf(shm[0], shm[1]), fmaxf(shm[2], shm[3]));
    float e0 = expf(v0 - M4), e1 = expf(v1 - M4);
    float su = waveSum(e0 + e1);
    if (ln == 0) shs[wv] = su;
    __syncthreads();
    float inv = 1.0f / (shs[0] + shs[1] + shs[2] + shs[3]);
    p[t] = (bf16_t)(e0 * inv);
    p[t + 256] = (bf16_t)(e1 * inv);
}

// ---------------- depthwise o_dw mix ----------------
__global__ __launch_bounds__(256)
void odw_k(const float* __restrict__ t, const float* __restrict__ dw, float* __restrict__ o)
{
    long idx = (long)blockIdx.x * 256 + threadIdx.x;
    long fw = idx & (FW - 1);
    int dch = (idx >> 19) & (M_ - 1);
    long b = idx >> 22;
    float acc = 0.f;
    #pragma unroll
    for (int c = 0; c < M_; ++c)
        acc += t[(b * M_ + c) * FW + fw] * dw[dch * M_ + c];
    o[idx] = acc;
}

// ---------------- multichannel layernorm over F axis ----------------
__global__ __launch_bounds__(256)
void mcln_k(const float* __restrict__ in, const float* __restrict__ gam,
            const float* __restrict__ bet, float* __restrict__ o1, float* __restrict__ o2)
{
    int wi = threadIdx.x & 31, fg = threadIdx.x >> 5;
    int w0 = blockIdx.x * 32;
    int c = blockIdx.y, b = blockIdx.z;
    long base = ((long)b * C_ + c) * FW + w0 + wi;
    float s = 0.f, q = 0.f;
    for (int f = fg; f < F_; f += 8) {
        float v = in[base + (long)f * W_];
        s += v; q += v * v;
    }
    __shared__ float rs[8][33], rq[8][33];
    __shared__ float mu_s[32], inv_s[32];
    rs[fg][wi] = s; rq[fg][wi] = q;
    __syncthreads();
    if (fg == 0) {
        float ts = 0.f, tq = 0.f;
        for (int g = 0; g < 8; ++g) { ts += rs[g][wi]; tq += rq[g][wi]; }
        float mu = ts * (1.0f / F_);
        float var = tq * (1.0f / F_) - mu * mu;
        mu_s[wi] = mu;
        inv_s[wi] = rsqrtf(var + 1e-5f);
    }
    __syncthreads();
    float mu = mu_s[wi], inv = inv_s[wi];
    for (int f = fg; f < F_; f += 8) {
        float v = in[base + (long)f * W_];
        float r = (v - mu) * inv * gam[c * F_ + f] + bet[c * F_ + f];
        long oi = base + (long)f * W_;
        o1[oi] = r;
        if (o2) o2[oi] = r;
    }
}

extern "C" void kernel_launch(void* const* d_in, const int* in_sizes, int n_in,
                              void* d_out, int out_size, void* d_ws, size_t ws_size,
                              hipStream_t stream) {
    (void)in_sizes; (void)n_in; (void)out_size; (void)ws_size;
    const float* x        = (const float*)d_in[0];
    const float* prev_qk  = (const float*)d_in[1];
    const float* qconv_w  = (const float*)d_in[2];
    const float* qconv_b  = (const float*)d_in[3];
    const float* q_pw     = (const float*)d_in[4];
    const float* kconv_w  = (const float*)d_in[5];
    const float* kconv_b  = (const float*)d_in[6];
    const float* k_pw     = (const float*)d_in[7];
    const float* vconv_w  = (const float*)d_in[8];
    const float* vconv_b  = (const float*)d_in[9];
    const float* v_pw     = (const float*)d_in[10];
    const float* o_pw     = (const float*)d_in[11];
    const float* o_dw     = (const float*)d_in[12];
    const float* oproj_w  = (const float*)d_in[13];
    const float* oproj_b  = (const float*)d_in[14];
    const float* n1_w     = (const float*)d_in[15];
    const float* n1_b     = (const float*)d_in[16];
    const float* c1_w     = (const float*)d_in[17];
    const float* c1_b     = (const float*)d_in[18];
    const float* c2_w     = (const float*)d_in[19];
    const float* c2_b     = (const float*)d_in[20];
    const float* n2_w     = (const float*)d_in[21];
    const float* n2_b     = (const float*)d_in[22];

    float* out    = (float*)d_out;
    float* qk_out = out + 16777216L;

    // workspace layout (352.3 MB total)
    char* wsb = (char*)d_ws;
    bf16_t* Wq = (bf16_t*)wsb;            // 8388608 elems each
    bf16_t* Wk = Wq + 8388608L;
    bf16_t* Wv = Wk + 8388608L;
    bf16_t* Wo = Wv + 8388608L;
    bf16_t* XT = Wo + 8388608L;           // conv out transposed bf16 [16][W][F]
    bf16_t* QR = XT + 8388608L;           // (BM,NH,W,HD) bf16
    bf16_t* KR = QR + 8388608L;
    bf16_t* VL = KR + 8388608L;           // v mclin out bf16 [16][F][W] (== V^T tiles)
    bf16_t* AT = VL + 8388608L;           // attn out transposed bf16 [B M][W][F]
    bf16_t* SH = AT + 8388608L;           // 33554432: P bf16, later c1out bf16
    float*  F0 = (float*)(wsb + 218103808L);
    float*  F1 = F0 + 8388608L;
    float*  F2 = F1 + 8388608L;
    float*  F3 = F2 + 8388608L;

    const dim3 cgrid(W_ / 32, F_ / 8, B_);       // conv grids (CIN=8-ish)
    const dim3 tgrid(16, 32, 16);                // transpose grid
    const dim3 ggrid(4, 8, 16);                  // mclin gemm grid
    const long BIG = 1 << 30;

    // weights -> bf16
    cvt_k<<<8192, 256, 0, stream>>>(q_pw, Wq, 2097152);
    cvt_k<<<8192, 256, 0, stream>>>(k_pw, Wk, 2097152);
    cvt_k<<<8192, 256, 0, stream>>>(v_pw, Wv, 2097152);
    cvt_k<<<8192, 256, 0, stream>>>(o_pw, Wo, 2097152);

    // ---- Q path ----
    conv3x3_lds_k<float, 8, 8, 0, 0><<<cgrid, 256, 0, stream>>>(x, 8, nullptr, qconv_w, qconv_b, nullptr, F0);
    tcvt_k<<<tgrid, 256, 0, stream>>>(F0, XT);
    gemm_mfma_k<0, 0><<<ggrid, 256, 0, stream>>>(Wq, XT, F1, nullptr, 1.f,
        F_, F_, F_, W_, 1048576L, 524288L, 524288L, 0L, 1, 0L, 8);
    rope_t_k<<<32768, 256, 0, stream>>>(F1, QR);

    // ---- K path ----
    conv3x3_lds_k<float, 8, 8, 0, 0><<<cgrid, 256, 0, stream>>>(x, 8, nullptr, kconv_w, kconv_b, nullptr, F0);
    tcvt_k<<<tgrid, 256, 0, stream>>>(F0, XT);
    gemm_mfma_k<0, 0><<<ggrid, 256, 0, stream>>>(Wk, XT, F1, nullptr, 1.f,
        F_, F_, F_, W_, 1048576L, 524288L, 524288L, 0L, 1, 0L, 8);
    rope_t_k<<<32768, 256, 0, stream>>>(F1, KR);

    // ---- V path (bf16 out, [F][W] == V^T per head) ----
    conv3x3_lds_k<float, 8, 8, 0, 0><<<cgrid, 256, 0, stream>>>(x, 8, nullptr, vconv_w, vconv_b, nullptr, F0);
    tcvt_k<<<tgrid, 256, 0, stream>>>(F0, XT);
    gemm_mfma_k<0, 1><<<ggrid, 256, 0, stream>>>(Wv, XT, VL, nullptr, 1.f,
        F_, F_, F_, W_, 1048576L, 524288L, 524288L, 0L, 1, 0L, 8);

    // ---- qk = QK^T/32 + prev_qk -> qk_out (fp32) ----
    gemm_mfma_k<1, 0><<<dim3(4, 4, 128), 256, 0, stream>>>(QR, KR, qk_out, prev_qk,
        0.03125f, HD_, HD_, HD_, W_, 65536L, 65536L, 262144L, 0L, 1, 262144L, (int)BIG);

    // ---- softmax -> P bf16 ----
    softmax_k<<<65536, 256, 0, stream>>>(qk_out, SH);

    // ---- a = P V  (write directly as a_feat^T bf16 [bm][w][f]) ----
    gemm_mfma_k<0, 1><<<dim3(1, 4, 128), 256, 0, stream>>>(SH, VL, AT, nullptr, 1.f,
        W_, W_, W_, F_, 262144L, 65536L, 524288L, 128L, 8, 0L, (int)BIG);

    // ---- o linear: t = o_pw * a_feat -> F0 fp32 ----
    gemm_mfma_k<0, 0><<<ggrid, 256, 0, stream>>>(Wo, AT, F0, nullptr, 1.f,
        F_, F_, F_, W_, 1048576L, 524288L, 524288L, 0L, 1, 0L, 8);

    // ---- depthwise mix ----
    odw_k<<<32768, 256, 0, stream>>>(F0, o_dw, F1);

    // ---- oproj conv over concat(x, a2) + x residual -> pre1 (F2) ----
    conv3x3_lds_k<float, 16, 8, 0, 0><<<cgrid, 256, 0, stream>>>(x, 8, F1, oproj_w, oproj_b, x, F2);

    // ---- hid = mcln(pre1) -> F3 ----
    mcln_k<<<dim3(16, 8, 2), 256, 0, stream>>>(F2, n1_w, n1_b, F3, nullptr);

    // ---- c1 conv + gelu -> SH bf16 ----
    conv3x3_lds_k<float, 8, 32, 1, 1><<<cgrid, 256, 0, stream>>>(F3, 8, nullptr, c1_w, c1_b, nullptr, SH);
    // ---- c2 conv + hid residual -> pre2 (F2) ----
    conv3x3_lds_k<bf16_t, 32, 8, 0, 0><<<cgrid, 256, 0, stream>>>(SH, 32, nullptr, c2_w, c2_b, F3, F2);

    // ---- out = mcln(pre2) -> both output copies ----
    mcln_k<<<dim3(16, 8, 2), 256, 0, stream>>>(F2, n2_w, n2_b, out, out + 8388608L);
}

// Round 6
// 812.774 us; speedup vs baseline: 7.3131x; 1.6724x over previous
//
#include <hip/hip_runtime.h>
#include <math.h>

#define B_ 2
#define C_ 8
#define M_ 8
#define NH_ 8
#define F_ 1024
#define W_ 512
#define HD_ 128
#define FW 524288L  // F_*W_
#define PF_ 1026
#define PW_ 514

typedef __bf16 bf16_t;
typedef __bf16 bf16x8 __attribute__((ext_vector_type(8)));
typedef __bf16 bf16x4 __attribute__((ext_vector_type(4)));
typedef float f32x4 __attribute__((ext_vector_type(4)));

__device__ __forceinline__ void gload16(const void* g, void* l) {
    __builtin_amdgcn_global_load_lds(
        (const __attribute__((address_space(1))) unsigned int*)g,
        (__attribute__((address_space(3))) unsigned int*)l,
        16, 0, 0);
}

__device__ __forceinline__ float gelu_f(float v) {
    return 0.5f * v * (1.0f + erff(v * 0.70710678118f));
}

// ---------------- pad+stage x -> channels-last bf16 [B][PF][PW][8] ----------------
__global__ __launch_bounds__(256)
void pad_stage_k(const float* __restrict__ x, bf16_t* __restrict__ px)
{
    long i = (long)blockIdx.x * 256 + threadIdx.x;
    if (i >= (long)B_ * PF_ * PW_) return;
    int wc = (int)(i % PW_);
    long t = i / PW_;
    int fr = (int)(t % PF_);
    int b  = (int)(t / PF_);
    bf16x8 v = {};
    if (fr >= 1 && fr <= F_ && wc >= 1 && wc <= W_) {
        const float* s = x + (long)b * 8 * FW + (long)(fr - 1) * W_ + (wc - 1);
        #pragma unroll
        for (int c = 0; c < 8; ++c) v[c] = (bf16_t)s[c * FW];
    }
    *(bf16x8*)&px[i * 8] = v;
}

// ---------------- zero borders of two 8-ch padded buffers ----------------
__global__ __launch_bounds__(256)
void borderz8_k(bf16_t* __restrict__ p8a, bf16_t* __restrict__ p8b)
{
    int i = blockIdx.x * 256 + threadIdx.x;
    if (i >= 2 * 3076) return;
    int b = i / 3076, p = i % 3076;
    int fr, wc;
    if (p < 514)       { fr = 0;    wc = p; }
    else if (p < 1028) { fr = 1025; wc = p - 514; }
    else if (p < 2052) { fr = 1 + (p - 1028); wc = 0; }
    else               { fr = 1 + (p - 2052); wc = 513; }
    long pix = ((long)b * PF_ + fr) * PW_ + wc;
    bf16x8 z = {};
    *(bf16x8*)&p8a[pix * 8] = z;
    *(bf16x8*)&p8b[pix * 8] = z;
}

// ---------------- zero borders of one 32-ch padded buffer ----------------
__global__ __launch_bounds__(256)
void borderz32_k(bf16_t* __restrict__ p32)
{
    int i = blockIdx.x * 256 + threadIdx.x;
    if (i >= 2 * 3076) return;
    int b = i / 3076, p = i % 3076;
    int fr, wc;
    if (p < 514)       { fr = 0;    wc = p; }
    else if (p < 1028) { fr = 1025; wc = p - 514; }
    else if (p < 2052) { fr = 1 + (p - 1028); wc = 0; }
    else               { fr = 1 + (p - 2052); wc = 513; }
    long pix = ((long)b * PF_ + fr) * PW_ + wc;
    bf16x8 z = {};
    #pragma unroll
    for (int k = 0; k < 4; ++k) *(bf16x8*)&p32[pix * 32 + k * 8] = z;
}

// ---------------- prep conv A-matrices (weights -> [3][M16][KW] bf16) ----------------
__global__ void aprep_k(const float* __restrict__ qw, const float* __restrict__ kw,
                        const float* __restrict__ vw, const float* __restrict__ ow,
                        const float* __restrict__ c1w, const float* __restrict__ c2w,
                        const float* __restrict__ qb, const float* __restrict__ kb,
                        const float* __restrict__ vb,
                        bf16_t* __restrict__ a_qkv, bf16_t* __restrict__ a_op,
                        bf16_t* __restrict__ a_c1, bf16_t* __restrict__ a_c2,
                        float* __restrict__ bias_qkv)
{
    int mode = blockIdx.y;
    int i = blockIdx.x * 256 + threadIdx.x;
    if (mode == 0) {              // qkv: [3][32][32]
        if (i < 3072) {
            int k = i & 31, co = (i >> 5) & 31, df = i >> 10;
            int tap = k >> 3, ci = k & 7;
            float v = 0.f;
            if (tap < 3) {
                if (co < 8)       v = qw[((co * 8 + ci) * 3 + df) * 3 + tap];
                else if (co < 16) v = kw[(((co - 8) * 8 + ci) * 3 + df) * 3 + tap];
                else if (co < 24) v = vw[(((co - 16) * 8 + ci) * 3 + df) * 3 + tap];
            }
            a_qkv[i] = (bf16_t)v;
        }
        if (i < 32) bias_qkv[i] = (i < 8) ? qb[i] : (i < 16) ? kb[i - 8] : (i < 24) ? vb[i - 16] : 0.f;
    } else if (mode == 1) {       // oproj: [3][16][64]
        if (i < 3072) {
            int k = i & 63, co = (i >> 6) & 15, df = i >> 10;
            int src = k >> 5, r = k & 31, tap = r >> 3, ci = src * 8 + (r & 7);
            float v = 0.f;
            if (co < 8 && tap < 3) v = ow[((co * 16 + ci) * 3 + df) * 3 + tap];
            a_op[i] = (bf16_t)v;
        }
    } else if (mode == 2) {       // c1: [3][32][32]
        if (i < 3072) {
            int k = i & 31, co = (i >> 5) & 31, df = i >> 10;
            int tap = k >> 3, ci = k & 7;
            float v = (tap < 3) ? c1w[((co * 8 + ci) * 3 + df) * 3 + tap] : 0.f;
            a_c1[i] = (bf16_t)v;
        }
    } else {                      // c2: [3][16][96]
        if (i < 4608) {
            int k = i % 96, co = (i / 96) & 15, df = i / (96 * 16);
            int tap = k >> 5, ci = k & 31;
            float v = (co < 8) ? c2w[((co * 32 + ci) * 3 + df) * 3 + tap] : 0.f;
            a_c2[i] = (bf16_t)v;
        }
    }
}

// ---------------- MFMA shift-GEMM conv ----------------
template<int CIN, int KSTEPS, int MFRAGS, int DUAL, int EPI>
__global__ __launch_bounds__(256)
void convg_k(const bf16_t* __restrict__ px0, const bf16_t* __restrict__ px1,
             const bf16_t* __restrict__ Ab, const float* __restrict__ bias,
             const float* __restrict__ resid, void* __restrict__ outp)
{
    const int f = blockIdx.y, b = blockIdx.z;
    const int tid = threadIdx.x, lane = tid & 63, wid = tid >> 6;
    const int l15 = lane & 15, l4 = lane >> 4;
    const int wbase = blockIdx.x * 256 + wid * 64;
    const int KW = KSTEPS * 32, M16 = MFRAGS * 16;

    bf16x8 af[3][MFRAGS][KSTEPS];
    #pragma unroll
    for (int df = 0; df < 3; ++df)
        #pragma unroll
        for (int mf = 0; mf < MFRAGS; ++mf)
            #pragma unroll
            for (int kk = 0; kk < KSTEPS; ++kk)
                af[df][mf][kk] = *(const bf16x8*)&Ab[(long)(df * M16 + mf * 16 + l15) * KW + kk * 32 + l4 * 8];

    f32x4 acc[MFRAGS][4];
    #pragma unroll
    for (int mf = 0; mf < MFRAGS; ++mf)
        #pragma unroll
        for (int nf = 0; nf < 4; ++nf)
            acc[mf][nf] = (f32x4){0.f, 0.f, 0.f, 0.f};

    #pragma unroll
    for (int df = 0; df < 3; ++df) {
        const long rowb = ((long)(b * PF_ + f + df)) * PW_ * CIN;
        #pragma unroll
        for (int nf = 0; nf < 4; ++nf) {
            const int wp = wbase + nf * 16 + l15;
            #pragma unroll
            for (int kk = 0; kk < KSTEPS; ++kk) {
                const bf16_t* src = (DUAL && kk == 1) ? px1 : px0;
                long addr = (CIN == 8) ? rowb + (long)(wp + l4) * 8
                                       : rowb + (long)(wp + kk) * 32 + l4 * 8;
                bf16x8 bv = *(const bf16x8*)&src[addr];
                #pragma unroll
                for (int mf = 0; mf < MFRAGS; ++mf)
                    acc[mf][nf] = __builtin_amdgcn_mfma_f32_16x16x32_bf16(
                        af[df][mf][kk], bv, acc[mf][nf], 0, 0, 0);
            }
        }
    }

    #pragma unroll
    for (int mf = 0; mf < MFRAGS; ++mf) {
        #pragma unroll
        for (int nf = 0; nf < 4; ++nf) {
            const int wp = wbase + nf * 16 + l15;
            if (EPI == 2) {
                const int cob = mf * 16 + l4 * 4;
                bf16x4 ov;
                #pragma unroll
                for (int r = 0; r < 4; ++r)
                    ov[r] = (bf16_t)gelu_f(acc[mf][nf][r] + bias[cob + r]);
                *(bf16x4*)&((bf16_t*)outp)[(((long)(b * PF_ + f + 1)) * PW_ + wp + 1) * 32 + cob] = ov;
            } else {
                #pragma unroll
                for (int r = 0; r < 4; ++r) {
                    const int co = mf * 16 + l4 * 4 + r;
                    float v = acc[mf][nf][r];
                    if (EPI == 0) {
                        if (co < 24)
                            ((bf16_t*)outp)[((long)(b * 24 + co)) * FW + (long)f * W_ + wp] = (bf16_t)(v + bias[co]);
                    } else {
                        if (co < 8) {
                            long oi = ((long)(b * 8 + co)) * FW + (long)f * W_ + wp;
                            ((float*)outp)[oi] = v + bias[co] + resid[oi];
                        }
                    }
                }
            }
        }
    }
}

// ---------------- bf16 MFMA GEMM: C = A(MxK) * B^T-stored(NxK) ----------------
template<int EPI, int OUTBF>
__global__ __launch_bounds__(256)
void gemm_mfma_k(const bf16_t* __restrict__ Ab, const bf16_t* __restrict__ Bb,
                 void* __restrict__ Cb, const float* __restrict__ Addb,
                 float scale, int Kdim, int lda, int ldb, int ldc,
                 long sA, long sB, long sC_hi, long sC_lo, int zdivC,
                 long sAdd, int aMod)
{
    __shared__ bf16_t sAt[4096];
    __shared__ bf16_t sBt[4096];

    const int z = blockIdx.z;
    const bf16_t* A = Ab + (long)(z % aMod) * sA;
    const bf16_t* B = Bb + (long)z * sB;
    const int m0 = blockIdx.y * 128;
    const int n0 = blockIdx.x * 128;
    const int tid = threadIdx.x;
    const int lane = tid & 63, wid = tid >> 6;
    const int wr = (wid >> 1) * 64, wc = (wid & 1) * 64;
    const int l15 = lane & 15, l4 = lane >> 4;

    f32x4 acc[4][4];
    #pragma unroll
    for (int m = 0; m < 4; ++m)
        #pragma unroll
        for (int n = 0; n < 4; ++n)
            acc[m][n] = (f32x4){0.f, 0.f, 0.f, 0.f};

    const int srow = tid >> 2;
    const int scol = (tid & 3) * 8;
    const long gA0 = (long)(m0 + srow) * lda + scol;
    const long gA1 = (long)(m0 + 64 + srow) * lda + scol;
    const long gB0 = (long)(n0 + srow) * ldb + scol;
    const long gB1 = (long)(n0 + 64 + srow) * ldb + scol;
    bf16_t* lA = sAt + wid * 512;
    bf16_t* lB = sBt + wid * 512;

    for (int k0 = 0; k0 < Kdim; k0 += 32) {
        __syncthreads();
        gload16(A + gA0 + k0, lA);
        gload16(A + gA1 + k0, lA + 2048);
        gload16(B + gB0 + k0, lB);
        gload16(B + gB1 + k0, lB + 2048);
        __syncthreads();

        bf16x8 afr[4], bfr[4];
        #pragma unroll
        for (int m = 0; m < 4; ++m)
            afr[m] = *(const bf16x8*)&sAt[(wr + m * 16 + l15) * 32 + l4 * 8];
        #pragma unroll
        for (int n = 0; n < 4; ++n)
            bfr[n] = *(const bf16x8*)&sBt[(wc + n * 16 + l15) * 32 + l4 * 8];
        #pragma unroll
        for (int m = 0; m < 4; ++m)
            #pragma unroll
            for (int n = 0; n < 4; ++n)
                acc[m][n] = __builtin_amdgcn_mfma_f32_16x16x32_bf16(
                    afr[m], bfr[n], acc[m][n], 0, 0, 0);
    }

    const long zc = (long)(z / zdivC) * sC_hi + (long)(z % zdivC) * sC_lo;
    #pragma unroll
    for (int m = 0; m < 4; ++m) {
        #pragma unroll
        for (int n = 0; n < 4; ++n) {
            #pragma unroll
            for (int r = 0; r < 4; ++r) {
                int row = m0 + wr + m * 16 + l4 * 4 + r;
                int col = n0 + wc + n * 16 + l15;
                float v = acc[m][n][r];
                if (EPI) v = v * scale + Addb[(long)z * sAdd + (long)row * ldc + col];
                long cidx = zc + (long)row * ldc + col;
                if (OUTBF) ((bf16_t*)Cb)[cidx] = (bf16_t)v;
                else       ((float*)Cb)[cidx]  = v;
            }
        }
    }
}

// ---------------- transpose+cvt: bf16 planar [slice][F][W] -> bf16 [z][W][F] ----------------
__global__ __launch_bounds__(256)
void tcvt_k(const bf16_t* __restrict__ in, bf16_t* __restrict__ outp, int smul, int sbase)
{
    __shared__ float tile[32][33];
    const int w0 = blockIdx.x * 32, f0 = blockIdx.y * 32;
    const int z = blockIdx.z;
    const int inSlice = (z >> 3) * smul + sbase + (z & 7);
    const long ibase = (long)inSlice * FW;
    const long obase = (long)z * FW;
    const int tx = threadIdx.x & 31, ty = threadIdx.x >> 5;
    #pragma unroll
    for (int i = 0; i < 4; ++i)
        tile[ty + i * 8][tx] = (float)in[ibase + (long)(f0 + ty + i * 8) * W_ + w0 + tx];
    __syncthreads();
    #pragma unroll
    for (int i = 0; i < 4; ++i)
        outp[obase + (long)(w0 + ty + i * 8) * F_ + f0 + tx] = (bf16_t)tile[tx][ty + i * 8];
}

// ---------------- flat fp32 -> bf16 ----------------
__global__ __launch_bounds__(256)
void cvt_k(const float* __restrict__ in, bf16_t* __restrict__ o, int n4)
{
    int i = blockIdx.x * 256 + threadIdx.x;
    if (i < n4) {
        float4 v = ((const float4*)in)[i];
        bf16x4 r = { (bf16_t)v.x, (bf16_t)v.y, (bf16_t)v.z, (bf16_t)v.w };
        *(bf16x4*)&o[(long)i * 4] = r;
    }
}

// ---------------- rope + heads transpose, bf16 out ----------------
__global__ __launch_bounds__(256)
void rope_t_k(const float* __restrict__ in, bf16_t* __restrict__ outp)
{
    long idx = (long)blockIdx.x * 256 + threadIdx.x;
    int d = idx & (HD_ - 1);
    int w = (idx >> 7) & (W_ - 1);
    int n = (idx >> 16) & (NH_ - 1);
    long bm = idx >> 19;
    long fin = bm * FW + (long)(n * HD_ + d) * W_ + w;
    float v = in[fin];
    int p = d >> 1;
    float inv = expf(-(float)p * 0.14391156507f);
    float ang = (float)w * inv;
    float cc, ss;
    sincosf(ang, &cc, &ss);
    float partner = (d & 1) ? in[fin - W_] : in[fin + W_];
    float xr = (d & 1) ? partner : -partner;
    v = v * cc + xr * ss;
    outp[idx] = (bf16_t)v;
}

// ---------------- softmax over last dim (512), bf16 out ----------------
__device__ inline float waveMax(float v) {
    #pragma unroll
    for (int o = 32; o >= 1; o >>= 1) v = fmaxf(v, __shfl_xor(v, o, 64));
    return v;
}
__device__ inline float waveSum(float v) {
    #pragma unroll
    for (int o = 32; o >= 1; o >>= 1) v += __shfl_xor(v, o, 64);
    return v;
}

__global__ __launch_bounds__(256)
void softmax_k(const float* __restrict__ S, bf16_t* __restrict__ P)
{
    long row = blockIdx.x;
    const float* s = S + row * 512;
    bf16_t* p = P + row * 512;
    int t = threadIdx.x;
    float v0 = s[t], v1 = s[t + 256];
    int wv = t >> 6, ln = t & 63;
    __shared__ float shm[4], shs[4];
    float m = waveMax(fmaxf(v0, v1));
    if (ln == 0) shm[wv] = m;
    __syncthreads();
    float M4 = fmaxf(fmaxf(shm[0], shm[1]), fmaxf(shm[2], shm[3]));
    float e0 = expf(v0 - M4), e1 = expf(v1 - M4);
    float su = waveSum(e0 + e1);
    if (ln == 0) shs[wv] = su;
    __syncthreads();
    float inv = 1.0f / (shs[0] + shs[1] + shs[2] + shs[3]);
    p[t] = (bf16_t)(e0 * inv);
    p[t + 256] = (bf16_t)(e1 * inv);
}

// ---------------- depthwise o_dw mix -> channels-last bf16 ----------------
__global__ __launch_bounds__(256)
void odw_k(const float* __restrict__ t, const float* __restrict__ dw, bf16_t* __restrict__ px)
{
    long i = (long)blockIdx.x * 256 + threadIdx.x;
    int w = (int)(i & (W_ - 1));
    long q = i >> 9;
    int f = (int)(q & (F_ - 1));
    int b = (int)(q >> 10);
    const float* s = t + (long)b * 8 * FW + (long)f * W_ + w;
    float tv[8];
    #pragma unroll
    for (int c = 0; c < 8; ++c) tv[c] = s[c * FW];
    bf16x8 o;
    #pragma unroll
    for (int d = 0; d < 8; ++d) {
        float a = 0.f;
        #pragma unroll
        for (int c = 0; c < 8; ++c) a += tv[c] * dw[d * 8 + c];
        o[d] = (bf16_t)a;
    }
    *(bf16x8*)&px[(((long)b * PF_ + f + 1) * PW_ + w + 1) * 8] = o;
}

// ---------------- fp32 planar [b][8][F][W] -> channels-last bf16 ----------------
__global__ __launch_bounds__(256)
void chl8_k(const float* __restrict__ in, bf16_t* __restrict__ px)
{
    long i = (long)blockIdx.x * 256 + threadIdx.x;
    int w = (int)(i & (W_ - 1));
    long q = i >> 9;
    int f = (int)(q & (F_ - 1));
    int b = (int)(q >> 10);
    const float* s = in + (long)b * 8 * FW + (long)f * W_ + w;
    bf16x8 v;
    #pragma unroll
    for (int c = 0; c < 8; ++c) v[c] = (bf16_t)s[c * FW];
    *(bf16x8*)&px[(((long)b * PF_ + f + 1) * PW_ + w + 1) * 8] = v;
}

// ---------------- multichannel layernorm over F axis ----------------
__global__ __launch_bounds__(256)
void mcln_k(const float* __restrict__ in, const float* __restrict__ gam,
            const float* __restrict__ bet, float* __restrict__ o1, float* __restrict__ o2)
{
    int wi = threadIdx.x & 31, fg = threadIdx.x >> 5;
    int w0 = blockIdx.x * 32;
    int c = blockIdx.y, b = blockIdx.z;
    long base = ((long)b * C_ + c) * FW + w0 + wi;
    float s = 0.f, q = 0.f;
    for (int f = fg; f < F_; f += 8) {
        float v = in[base + (long)f * W_];
        s += v; q += v * v;
    }
    __shared__ float rs[8][33], rq[8][33];
    __shared__ float mu_s[32], inv_s[32];
    rs[fg][wi] = s; rq[fg][wi] = q;
    __syncthreads();
    if (fg == 0) {
        float ts = 0.f, tq = 0.f;
        for (int g = 0; g < 8; ++g) { ts += rs[g][wi]; tq += rq[g][wi]; }
        float mu = ts * (1.0f / F_);
        float var = tq * (1.0f / F_) - mu * mu;
        mu_s[wi] = mu;
        inv_s[wi] = rsqrtf(var + 1e-5f);
    }
    __syncthreads();
    float mu = mu_s[wi], inv = inv_s[wi];
    for (int f = fg; f < F_; f += 8) {
        float v = in[base + (long)f * W_];
        float r = (v - mu) * inv * gam[c * F_ + f] + bet[c * F_ + f];
        long oi = base + (long)f * W_;
        o1[oi] = r;
        if (o2) o2[oi] = r;
    }
}

extern "C" void kernel_launch(void* const* d_in, const int* in_sizes, int n_in,
                              void* d_out, int out_size, void* d_ws, size_t ws_size,
                              hipStream_t stream) {
    (void)in_sizes; (void)n_in; (void)out_size; (void)ws_size;
    const float* x        = (const float*)d_in[0];
    const float* prev_qk  = (const float*)d_in[1];
    const float* qconv_w  = (const float*)d_in[2];
    const float* qconv_b  = (const float*)d_in[3];
    const float* q_pw     = (const float*)d_in[4];
    const float* kconv_w  = (const float*)d_in[5];
    const float* kconv_b  = (const float*)d_in[6];
    const float* k_pw     = (const float*)d_in[7];
    const float* vconv_w  = (const float*)d_in[8];
    const float* vconv_b  = (const float*)d_in[9];
    const float* v_pw     = (const float*)d_in[10];
    const float* o_pw     = (const float*)d_in[11];
    const float* o_dw     = (const float*)d_in[12];
    const float* oproj_w  = (const float*)d_in[13];
    const float* oproj_b  = (const float*)d_in[14];
    const float* n1_w     = (const float*)d_in[15];
    const float* n1_b     = (const float*)d_in[16];
    const float* c1_w     = (const float*)d_in[17];
    const float* c1_b     = (const float*)d_in[18];
    const float* c2_w     = (const float*)d_in[19];
    const float* c2_b     = (const float*)d_in[20];
    const float* n2_w     = (const float*)d_in[21];
    const float* n2_b     = (const float*)d_in[22];

    float* out    = (float*)d_out;
    float* qk_out = out + 16777216L;

    // -------- workspace layout (251.8 MB peak; all aliases lifetime-verified) --------
    // Phase legend: A prep | B qkv conv | C q/k/v mclin | D attention | E o+odw | F oproj | G ln1 | H ffn
    char* wsb = (char*)d_ws;
    bf16_t* PX8  = (bf16_t*)(wsb + 0L);            // 16,875,648+pad   live A..F
    bf16_t* Wq   = (bf16_t*)(wsb + 16876032L);     // 16,777,216      live A..C(q)
    bf16_t* Wk   = (bf16_t*)(wsb + 33653248L);     // 16,777,216      live A..C(k)
    bf16_t* Wv   = (bf16_t*)(wsb + 50430464L);     // 16,777,216      live A..C(v)
    bf16_t* Wo   = (bf16_t*)(wsb + 67207680L);     // 16,777,216      live A..E  (no longer clobbered!)
    bf16_t* QR   = (bf16_t*)(wsb + 83984896L);     // 16,777,216      live C..D(qk)
    bf16_t* KR   = (bf16_t*)(wsb + 100762112L);    // 16,777,216      live C..D(qk)
    bf16_t* VL   = (bf16_t*)(wsb + 117539328L);    // 16,777,216      live C..D(pv)
    float*  F1   = (float*) (wsb + 134316544L);    // 33,554,432      live C..E
    bf16_t* QKV  = (bf16_t*)(wsb + 167870976L);    // 50,331,648      live B..C
    bf16_t* XT   = (bf16_t*)(wsb + 218202624L);    // 16,777,216      live C
    bf16_t* SH   = (bf16_t*)(wsb + 167870976L);    // 67,108,864 (=QKV+XT, dead) live D — full P size now
    bf16_t* AT   = (bf16_t*)(wsb + 234979840L);    // 16,777,216      live D..E (disjoint from SH now)
    bf16_t* ABQ  = (bf16_t*)(wsb + 251757056L);    // AB block, live all
    bf16_t* ABO  = (bf16_t*)(wsb + 251757056L + 16384L);
    bf16_t* ABC1 = (bf16_t*)(wsb + 251757056L + 32768L);
    bf16_t* ABC2 = (bf16_t*)(wsb + 251757056L + 49152L);
    float*  BQKV = (float*) (wsb + 251757056L + 65536L);
    float*  PRE  = (float*) (wsb + 83984896L);     // over QR+KR (dead after D)  live F..H
    float*  HID  = (float*) (wsb + 117539328L);    // over VL+F1-head (dead)     live G..H
    bf16_t* PXH  = (bf16_t*)(wsb + 151093760L);    // over F1-tail+SH-head (dead) live G..H
    bf16_t* PXA2 = (bf16_t*)(wsb + 184746624L);    // inside SH span (dead after PV) live E..F
    bf16_t* PXC1 = (bf16_t*)(wsb + 0L);            // over PX8+Wq..Wv (dead after F) live H

    const dim3 cvgrid(2, F_, B_);
    const dim3 tgrid(16, 32, 16);
    const dim3 ggrid(4, 8, 16);
    const long BIG = 1 << 30;

    // ---- A: weights -> bf16 (full 8,388,608 elems each); A-matrices; padded x ----
    cvt_k<<<8192, 256, 0, stream>>>(q_pw, Wq, 2097152);
    cvt_k<<<8192, 256, 0, stream>>>(k_pw, Wk, 2097152);
    cvt_k<<<8192, 256, 0, stream>>>(v_pw, Wv, 2097152);
    cvt_k<<<8192, 256, 0, stream>>>(o_pw, Wo, 2097152);
    aprep_k<<<dim3(18, 4), 256, 0, stream>>>(qconv_w, kconv_w, vconv_w, oproj_w, c1_w, c2_w,
                                             qconv_b, kconv_b, vconv_b,
                                             ABQ, ABO, ABC1, ABC2, BQKV);
    pad_stage_k<<<4121, 256, 0, stream>>>(x, PX8);

    // ---- B: fused q/k/v conv (M=24) ----
    convg_k<8, 1, 2, 0, 0><<<cvgrid, 256, 0, stream>>>(PX8, nullptr, ABQ, BQKV, nullptr, QKV);

    // ---- C: mclin q/k/v ----
    tcvt_k<<<tgrid, 256, 0, stream>>>(QKV, XT, 24, 0);
    gemm_mfma_k<0, 0><<<ggrid, 256, 0, stream>>>(Wq, XT, F1, nullptr, 1.f,
        F_, F_, F_, W_, 1048576L, 524288L, 524288L, 0L, 1, 0L, 8);
    rope_t_k<<<32768, 256, 0, stream>>>(F1, QR);

    tcvt_k<<<tgrid, 256, 0, stream>>>(QKV, XT, 24, 8);
    gemm_mfma_k<0, 0><<<ggrid, 256, 0, stream>>>(Wk, XT, F1, nullptr, 1.f,
        F_, F_, F_, W_, 1048576L, 524288L, 524288L, 0L, 1, 0L, 8);
    rope_t_k<<<32768, 256, 0, stream>>>(F1, KR);

    tcvt_k<<<tgrid, 256, 0, stream>>>(QKV, XT, 24, 16);
    gemm_mfma_k<0, 1><<<ggrid, 256, 0, stream>>>(Wv, XT, VL, nullptr, 1.f,
        F_, F_, F_, W_, 1048576L, 524288L, 524288L, 0L, 1, 0L, 8);

    // ---- D: attention ----
    gemm_mfma_k<1, 0><<<dim3(4, 4, 128), 256, 0, stream>>>(QR, KR, qk_out, prev_qk,
        0.03125f, HD_, HD_, HD_, W_, 65536L, 65536L, 262144L, 0L, 1, 262144L, (int)BIG);
    softmax_k<<<65536, 256, 0, stream>>>(qk_out, SH);
    gemm_mfma_k<0, 1><<<dim3(1, 4, 128), 256, 0, stream>>>(SH, VL, AT, nullptr, 1.f,
        W_, W_, W_, F_, 262144L, 65536L, 524288L, 128L, 8, 0L, (int)BIG);

    // ---- E: o linear + depthwise mix ----
    gemm_mfma_k<0, 0><<<ggrid, 256, 0, stream>>>(Wo, AT, F1, nullptr, 1.f,
        F_, F_, F_, W_, 1048576L, 524288L, 524288L, 0L, 1, 0L, 8);
    odw_k<<<4096, 256, 0, stream>>>(F1, o_dw, PXA2);
    borderz8_k<<<25, 256, 0, stream>>>(PXA2, PXH);   // F1/SH dead -> both regions free

    // ---- F: oproj conv (x ++ a2) + x residual -> pre1 ----
    convg_k<8, 2, 1, 1, 1><<<cvgrid, 256, 0, stream>>>(PX8, PXA2, ABO, oproj_b, x, PRE);
    borderz32_k<<<25, 256, 0, stream>>>(PXC1);       // PX8/Wq..Wv dead now

    // ---- G: hid = mcln(pre1) ----
    mcln_k<<<dim3(16, 8, 2), 256, 0, stream>>>(PRE, n1_w, n1_b, HID, nullptr);
    chl8_k<<<4096, 256, 0, stream>>>(HID, PXH);

    // ---- H: ffn ----
    convg_k<8, 1, 2, 0, 2><<<cvgrid, 256, 0, stream>>>(PXH, nullptr, ABC1, c1_b, nullptr, PXC1);
    convg_k<32, 3, 1, 0, 1><<<cvgrid, 256, 0, stream>>>(PXC1, nullptr, ABC2, c2_b, HID, PRE);
    mcln_k<<<dim3(16, 8, 2), 256, 0, stream>>>(PRE, n2_w, n2_b, out, out + 8388608L);
}

// Round 7
// 705.784 us; speedup vs baseline: 8.4217x; 1.1516x over previous
//
#include <hip/hip_runtime.h>
#include <math.h>

#define B_ 2
#define C_ 8
#define M_ 8
#define NH_ 8
#define F_ 1024
#define W_ 512
#define HD_ 128
#define FW 524288L  // F_*W_
#define PF_ 1026
#define PW_ 514

typedef __bf16 bf16_t;
typedef __bf16 bf16x8 __attribute__((ext_vector_type(8)));
typedef __bf16 bf16x4 __attribute__((ext_vector_type(4)));
typedef float f32x4 __attribute__((ext_vector_type(4)));

__device__ __forceinline__ void gload16(const void* g, void* l) {
    __builtin_amdgcn_global_load_lds(
        (const __attribute__((address_space(1))) unsigned int*)g,
        (__attribute__((address_space(3))) unsigned int*)l,
        16, 0, 0);
}

__device__ __forceinline__ float gelu_f(float v) {
    return 0.5f * v * (1.0f + erff(v * 0.70710678118f));
}

// ---------------- pad+stage x -> channels-last bf16 [B][PF][PW][8] ----------------
__global__ __launch_bounds__(256)
void pad_stage_k(const float* __restrict__ x, bf16_t* __restrict__ px)
{
    long i = (long)blockIdx.x * 256 + threadIdx.x;
    if (i >= (long)B_ * PF_ * PW_) return;
    int wc = (int)(i % PW_);
    long t = i / PW_;
    int fr = (int)(t % PF_);
    int b  = (int)(t / PF_);
    bf16x8 v = {};
    if (fr >= 1 && fr <= F_ && wc >= 1 && wc <= W_) {
        const float* s = x + (long)b * 8 * FW + (long)(fr - 1) * W_ + (wc - 1);
        #pragma unroll
        for (int c = 0; c < 8; ++c) v[c] = (bf16_t)s[c * FW];
    }
    *(bf16x8*)&px[i * 8] = v;
}

// ---------------- zero borders of two 8-ch padded buffers ----------------
__global__ __launch_bounds__(256)
void borderz8_k(bf16_t* __restrict__ p8a, bf16_t* __restrict__ p8b)
{
    int i = blockIdx.x * 256 + threadIdx.x;
    if (i >= 2 * 3076) return;
    int b = i / 3076, p = i % 3076;
    int fr, wc;
    if (p < 514)       { fr = 0;    wc = p; }
    else if (p < 1028) { fr = 1025; wc = p - 514; }
    else if (p < 2052) { fr = 1 + (p - 1028); wc = 0; }
    else               { fr = 1 + (p - 2052); wc = 513; }
    long pix = ((long)b * PF_ + fr) * PW_ + wc;
    bf16x8 z = {};
    *(bf16x8*)&p8a[pix * 8] = z;
    *(bf16x8*)&p8b[pix * 8] = z;
}

// ---------------- zero borders of one 32-ch padded buffer ----------------
__global__ __launch_bounds__(256)
void borderz32_k(bf16_t* __restrict__ p32)
{
    int i = blockIdx.x * 256 + threadIdx.x;
    if (i >= 2 * 3076) return;
    int b = i / 3076, p = i % 3076;
    int fr, wc;
    if (p < 514)       { fr = 0;    wc = p; }
    else if (p < 1028) { fr = 1025; wc = p - 514; }
    else if (p < 2052) { fr = 1 + (p - 1028); wc = 0; }
    else               { fr = 1 + (p - 2052); wc = 513; }
    long pix = ((long)b * PF_ + fr) * PW_ + wc;
    bf16x8 z = {};
    #pragma unroll
    for (int k = 0; k < 4; ++k) *(bf16x8*)&p32[pix * 32 + k * 8] = z;
}

// ---------------- prep conv A-matrices (weights -> [3][M16][KW] bf16) ----------------
__global__ void aprep_k(const float* __restrict__ qw, const float* __restrict__ kw,
                        const float* __restrict__ vw, const float* __restrict__ ow,
                        const float* __restrict__ c1w, const float* __restrict__ c2w,
                        const float* __restrict__ qb, const float* __restrict__ kb,
                        const float* __restrict__ vb,
                        bf16_t* __restrict__ a_qkv, bf16_t* __restrict__ a_op,
                        bf16_t* __restrict__ a_c1, bf16_t* __restrict__ a_c2,
                        float* __restrict__ bias_qkv)
{
    int mode = blockIdx.y;
    int i = blockIdx.x * 256 + threadIdx.x;
    if (mode == 0) {              // qkv: [3][32][32]
        if (i < 3072) {
            int k = i & 31, co = (i >> 5) & 31, df = i >> 10;
            int tap = k >> 3, ci = k & 7;
            float v = 0.f;
            if (tap < 3) {
                if (co < 8)       v = qw[((co * 8 + ci) * 3 + df) * 3 + tap];
                else if (co < 16) v = kw[(((co - 8) * 8 + ci) * 3 + df) * 3 + tap];
                else if (co < 24) v = vw[(((co - 16) * 8 + ci) * 3 + df) * 3 + tap];
            }
            a_qkv[i] = (bf16_t)v;
        }
        if (i < 32) bias_qkv[i] = (i < 8) ? qb[i] : (i < 16) ? kb[i - 8] : (i < 24) ? vb[i - 16] : 0.f;
    } else if (mode == 1) {       // oproj: [3][16][64]
        if (i < 3072) {
            int k = i & 63, co = (i >> 6) & 15, df = i >> 10;
            int src = k >> 5, r = k & 31, tap = r >> 3, ci = src * 8 + (r & 7);
            float v = 0.f;
            if (co < 8 && tap < 3) v = ow[((co * 16 + ci) * 3 + df) * 3 + tap];
            a_op[i] = (bf16_t)v;
        }
    } else if (mode == 2) {       // c1: [3][32][32]
        if (i < 3072) {
            int k = i & 31, co = (i >> 5) & 31, df = i >> 10;
            int tap = k >> 3, ci = k & 7;
            float v = (tap < 3) ? c1w[((co * 8 + ci) * 3 + df) * 3 + tap] : 0.f;
            a_c1[i] = (bf16_t)v;
        }
    } else {                      // c2: [3][16][96]
        if (i < 4608) {
            int k = i % 96, co = (i / 96) & 15, df = i / (96 * 16);
            int tap = k >> 5, ci = k & 31;
            float v = (co < 8) ? c2w[((co * 32 + ci) * 3 + df) * 3 + tap] : 0.f;
            a_c2[i] = (bf16_t)v;
        }
    }
}

// ---------------- MFMA shift-GEMM conv ----------------
// EPI 0: planar bf16 [b][24][F][W] + bias (rows<24)
// EPI 1: bf16 planar [b][8][F][W] = conv + bias + resid(fp32) (rows<8)
// EPI 2: gelu(conv+bias) -> channels-last [b][PF][PW][32] bf16
template<int CIN, int KSTEPS, int MFRAGS, int DUAL, int EPI>
__global__ __launch_bounds__(256)
void convg_k(const bf16_t* __restrict__ px0, const bf16_t* __restrict__ px1,
             const bf16_t* __restrict__ Ab, const float* __restrict__ bias,
             const float* __restrict__ resid, void* __restrict__ outp)
{
    const int f = blockIdx.y, b = blockIdx.z;
    const int tid = threadIdx.x, lane = tid & 63, wid = tid >> 6;
    const int l15 = lane & 15, l4 = lane >> 4;
    const int wbase = blockIdx.x * 256 + wid * 64;
    const int KW = KSTEPS * 32, M16 = MFRAGS * 16;

    bf16x8 af[3][MFRAGS][KSTEPS];
    #pragma unroll
    for (int df = 0; df < 3; ++df)
        #pragma unroll
        for (int mf = 0; mf < MFRAGS; ++mf)
            #pragma unroll
            for (int kk = 0; kk < KSTEPS; ++kk)
                af[df][mf][kk] = *(const bf16x8*)&Ab[(long)(df * M16 + mf * 16 + l15) * KW + kk * 32 + l4 * 8];

    f32x4 acc[MFRAGS][4];
    #pragma unroll
    for (int mf = 0; mf < MFRAGS; ++mf)
        #pragma unroll
        for (int nf = 0; nf < 4; ++nf)
            acc[mf][nf] = (f32x4){0.f, 0.f, 0.f, 0.f};

    #pragma unroll
    for (int df = 0; df < 3; ++df) {
        const long rowb = ((long)(b * PF_ + f + df)) * PW_ * CIN;
        #pragma unroll
        for (int nf = 0; nf < 4; ++nf) {
            const int wp = wbase + nf * 16 + l15;
            #pragma unroll
            for (int kk = 0; kk < KSTEPS; ++kk) {
                const bf16_t* src = (DUAL && kk == 1) ? px1 : px0;
                long addr = (CIN == 8) ? rowb + (long)(wp + l4) * 8
                                       : rowb + (long)(wp + kk) * 32 + l4 * 8;
                bf16x8 bv = *(const bf16x8*)&src[addr];
                #pragma unroll
                for (int mf = 0; mf < MFRAGS; ++mf)
                    acc[mf][nf] = __builtin_amdgcn_mfma_f32_16x16x32_bf16(
                        af[df][mf][kk], bv, acc[mf][nf], 0, 0, 0);
            }
        }
    }

    #pragma unroll
    for (int mf = 0; mf < MFRAGS; ++mf) {
        #pragma unroll
        for (int nf = 0; nf < 4; ++nf) {
            const int wp = wbase + nf * 16 + l15;
            if (EPI == 2) {
                const int cob = mf * 16 + l4 * 4;
                bf16x4 ov;
                #pragma unroll
                for (int r = 0; r < 4; ++r)
                    ov[r] = (bf16_t)gelu_f(acc[mf][nf][r] + bias[cob + r]);
                *(bf16x4*)&((bf16_t*)outp)[(((long)(b * PF_ + f + 1)) * PW_ + wp + 1) * 32 + cob] = ov;
            } else {
                #pragma unroll
                for (int r = 0; r < 4; ++r) {
                    const int co = mf * 16 + l4 * 4 + r;
                    float v = acc[mf][nf][r];
                    if (EPI == 0) {
                        if (co < 24)
                            ((bf16_t*)outp)[((long)(b * 24 + co)) * FW + (long)f * W_ + wp] = (bf16_t)(v + bias[co]);
                    } else {
                        if (co < 8) {
                            long oi = ((long)(b * 8 + co)) * FW + (long)f * W_ + wp;
                            ((bf16_t*)outp)[oi] = (bf16_t)(v + bias[co] + resid[oi]);
                        }
                    }
                }
            }
        }
    }
}

// ---------------- bf16 MFMA GEMM: C = A(MxK) * B^T-stored(NxK) ----------------
// EPI 0: plain store (OUTBF picks fp32/bf16)
// EPI 1: fp32 store of v*scale + Add[z]
// EPI 2: rope epilogue -> bf16 QR layout [z][8][512][128] (head = blockIdx.y)
template<int EPI, int OUTBF>
__global__ __launch_bounds__(256)
void gemm_mfma_k(const bf16_t* __restrict__ Ab, const bf16_t* __restrict__ Bb,
                 void* __restrict__ Cb, const float* __restrict__ Addb,
                 float scale, int Kdim, int lda, int ldb, int ldc,
                 long sA, long sB, long sC_hi, long sC_lo, int zdivC,
                 long sAdd, int aMod)
{
    __shared__ bf16_t sAt[4096];
    __shared__ bf16_t sBt[4096];

    const int z = blockIdx.z;
    const bf16_t* A = Ab + (long)(z % aMod) * sA;
    const bf16_t* B = Bb + (long)z * sB;
    const int m0 = blockIdx.y * 128;
    const int n0 = blockIdx.x * 128;
    const int tid = threadIdx.x;
    const int lane = tid & 63, wid = tid >> 6;
    const int wr = (wid >> 1) * 64, wc = (wid & 1) * 64;
    const int l15 = lane & 15, l4 = lane >> 4;

    f32x4 acc[4][4];
    #pragma unroll
    for (int m = 0; m < 4; ++m)
        #pragma unroll
        for (int n = 0; n < 4; ++n)
            acc[m][n] = (f32x4){0.f, 0.f, 0.f, 0.f};

    const int srow = tid >> 2;
    const int scol = (tid & 3) * 8;
    const long gA0 = (long)(m0 + srow) * lda + scol;
    const long gA1 = (long)(m0 + 64 + srow) * lda + scol;
    const long gB0 = (long)(n0 + srow) * ldb + scol;
    const long gB1 = (long)(n0 + 64 + srow) * ldb + scol;
    bf16_t* lA = sAt + wid * 512;
    bf16_t* lB = sBt + wid * 512;

    for (int k0 = 0; k0 < Kdim; k0 += 32) {
        __syncthreads();
        gload16(A + gA0 + k0, lA);
        gload16(A + gA1 + k0, lA + 2048);
        gload16(B + gB0 + k0, lB);
        gload16(B + gB1 + k0, lB + 2048);
        __syncthreads();

        bf16x8 afr[4], bfr[4];
        #pragma unroll
        for (int m = 0; m < 4; ++m)
            afr[m] = *(const bf16x8*)&sAt[(wr + m * 16 + l15) * 32 + l4 * 8];
        #pragma unroll
        for (int n = 0; n < 4; ++n)
            bfr[n] = *(const bf16x8*)&sBt[(wc + n * 16 + l15) * 32 + l4 * 8];
        #pragma unroll
        for (int m = 0; m < 4; ++m)
            #pragma unroll
            for (int n = 0; n < 4; ++n)
                acc[m][n] = __builtin_amdgcn_mfma_f32_16x16x32_bf16(
                    afr[m], bfr[n], acc[m][n], 0, 0, 0);
    }

    if (EPI == 2) {
        // rope + heads-transpose epilogue. d = head-local feature, col = w.
        #pragma unroll
        for (int m = 0; m < 4; ++m) {
            const int d0 = wr + m * 16 + l4 * 4;
            const float inv0 = __expf(-(float)(d0 >> 1) * 0.14391156507f);
            const float inv1 = __expf(-(float)((d0 >> 1) + 1) * 0.14391156507f);
            #pragma unroll
            for (int n = 0; n < 4; ++n) {
                const int col = n0 + wc + n * 16 + l15;
                float s0, c0, s1, c1;
                __sincosf((float)col * inv0, &s0, &c0);
                __sincosf((float)col * inv1, &s1, &c1);
                float v0 = acc[m][n][0], v1 = acc[m][n][1];
                float v2 = acc[m][n][2], v3 = acc[m][n][3];
                bf16x4 ov = { (bf16_t)(v0 * c0 - v1 * s0), (bf16_t)(v1 * c0 + v0 * s0),
                              (bf16_t)(v2 * c1 - v3 * s1), (bf16_t)(v3 * c1 + v2 * s1) };
                *(bf16x4*)&((bf16_t*)Cb)[(((long)z * 8 + blockIdx.y) * 512 + col) * 128 + d0] = ov;
            }
        }
        return;
    }

    const long zc = (long)(z / zdivC) * sC_hi + (long)(z % zdivC) * sC_lo;
    #pragma unroll
    for (int m = 0; m < 4; ++m) {
        #pragma unroll
        for (int n = 0; n < 4; ++n) {
            #pragma unroll
            for (int r = 0; r < 4; ++r) {
                int row = m0 + wr + m * 16 + l4 * 4 + r;
                int col = n0 + wc + n * 16 + l15;
                float v = acc[m][n][r];
                if (EPI == 1) v = v * scale + Addb[(long)z * sAdd + (long)row * ldc + col];
                long cidx = zc + (long)row * ldc + col;
                if (OUTBF) ((bf16_t*)Cb)[cidx] = (bf16_t)v;
                else       ((float*)Cb)[cidx]  = v;
            }
        }
    }
}

// ---------------- transpose+cvt: bf16 planar [slice][F][W] -> bf16 [z][W][F] ----------------
__global__ __launch_bounds__(256)
void tcvt_k(const bf16_t* __restrict__ in, bf16_t* __restrict__ outp, int smul, int sbase)
{
    __shared__ float tile[32][33];
    const int w0 = blockIdx.x * 32, f0 = blockIdx.y * 32;
    const int z = blockIdx.z;
    const int inSlice = (z >> 3) * smul + sbase + (z & 7);
    const long ibase = (long)inSlice * FW;
    const long obase = (long)z * FW;
    const int tx = threadIdx.x & 31, ty = threadIdx.x >> 5;
    #pragma unroll
    for (int i = 0; i < 4; ++i)
        tile[ty + i * 8][tx] = (float)in[ibase + (long)(f0 + ty + i * 8) * W_ + w0 + tx];
    __syncthreads();
    #pragma unroll
    for (int i = 0; i < 4; ++i)
        outp[obase + (long)(w0 + ty + i * 8) * F_ + f0 + tx] = (bf16_t)tile[tx][ty + i * 8];
}

// ---------------- flat fp32 -> bf16 ----------------
__global__ __launch_bounds__(256)
void cvt_k(const float* __restrict__ in, bf16_t* __restrict__ o, int n4)
{
    int i = blockIdx.x * 256 + threadIdx.x;
    if (i < n4) {
        float4 v = ((const float4*)in)[i];
        bf16x4 r = { (bf16_t)v.x, (bf16_t)v.y, (bf16_t)v.z, (bf16_t)v.w };
        *(bf16x4*)&o[(long)i * 4] = r;
    }
}

// ---------------- softmax: one wave per row of 512, bf16 out ----------------
__device__ inline float waveMax(float v) {
    #pragma unroll
    for (int o = 32; o >= 1; o >>= 1) v = fmaxf(v, __shfl_xor(v, o, 64));
    return v;
}
__device__ inline float waveSum(float v) {
    #pragma unroll
    for (int o = 32; o >= 1; o >>= 1) v += __shfl_xor(v, o, 64);
    return v;
}

__global__ __launch_bounds__(256)
void softmax_k(const float* __restrict__ S, bf16_t* __restrict__ P)
{
    const int wid = threadIdx.x >> 6, lane = threadIdx.x & 63;
    const long row = (long)blockIdx.x * 4 + wid;
    const float4* s4 = (const float4*)(S + row * 512);
    float4 a = s4[lane * 2], b = s4[lane * 2 + 1];
    float m = fmaxf(fmaxf(fmaxf(a.x, a.y), fmaxf(a.z, a.w)),
                    fmaxf(fmaxf(b.x, b.y), fmaxf(b.z, b.w)));
    m = waveMax(m);
    float e0 = __expf(a.x - m), e1 = __expf(a.y - m), e2 = __expf(a.z - m), e3 = __expf(a.w - m);
    float e4 = __expf(b.x - m), e5 = __expf(b.y - m), e6 = __expf(b.z - m), e7 = __expf(b.w - m);
    float su = waveSum(e0 + e1 + e2 + e3 + e4 + e5 + e6 + e7);
    float inv = 1.0f / su;
    bf16x8 o = { (bf16_t)(e0 * inv), (bf16_t)(e1 * inv), (bf16_t)(e2 * inv), (bf16_t)(e3 * inv),
                 (bf16_t)(e4 * inv), (bf16_t)(e5 * inv), (bf16_t)(e6 * inv), (bf16_t)(e7 * inv) };
    *(bf16x8*)(P + row * 512 + lane * 8) = o;
}

// ---------------- depthwise o_dw mix (bf16 in) -> channels-last bf16 ----------------
__global__ __launch_bounds__(256)
void odw_k(const bf16_t* __restrict__ t, const float* __restrict__ dw, bf16_t* __restrict__ px)
{
    long i = (long)blockIdx.x * 256 + threadIdx.x;
    int w = (int)(i & (W_ - 1));
    long q = i >> 9;
    int f = (int)(q & (F_ - 1));
    int b = (int)(q >> 10);
    const bf16_t* s = t + (long)b * 8 * FW + (long)f * W_ + w;
    float tv[8];
    #pragma unroll
    for (int c = 0; c < 8; ++c) tv[c] = (float)s[c * FW];
    bf16x8 o;
    #pragma unroll
    for (int d = 0; d < 8; ++d) {
        float a = 0.f;
        #pragma unroll
        for (int c = 0; c < 8; ++c) a += tv[c] * dw[d * 8 + c];
        o[d] = (bf16_t)a;
    }
    *(bf16x8*)&px[(((long)b * PF_ + f + 1) * PW_ + w + 1) * 8] = o;
}

// ---------------- multichannel layernorm over F axis (bf16 in) ----------------
// o1/o2: fp32 planar outputs (o2 nullable). px: optional channels-last bf16 padded.
template<typename TIN>
__global__ __launch_bounds__(256)
void mcln_k(const TIN* __restrict__ in, const float* __restrict__ gam,
            const float* __restrict__ bet, float* __restrict__ o1, float* __restrict__ o2,
            bf16_t* __restrict__ px)
{
    int wi = threadIdx.x & 31, fg = threadIdx.x >> 5;
    int w0 = blockIdx.x * 32;
    int c = blockIdx.y, b = blockIdx.z;
    long base = ((long)b * C_ + c) * FW + w0 + wi;
    float s = 0.f, q = 0.f;
    for (int f = fg; f < F_; f += 8) {
        float v = (float)in[base + (long)f * W_];
        s += v; q += v * v;
    }
    __shared__ float rs[8][33], rq[8][33];
    __shared__ float mu_s[32], inv_s[32];
    rs[fg][wi] = s; rq[fg][wi] = q;
    __syncthreads();
    if (fg == 0) {
        float ts = 0.f, tq = 0.f;
        for (int g = 0; g < 8; ++g) { ts += rs[g][wi]; tq += rq[g][wi]; }
        float mu = ts * (1.0f / F_);
        float var = tq * (1.0f / F_) - mu * mu;
        mu_s[wi] = mu;
        inv_s[wi] = rsqrtf(var + 1e-5f);
    }
    __syncthreads();
    float mu = mu_s[wi], inv = inv_s[wi];
    for (int f = fg; f < F_; f += 8) {
        float v = (float)in[base + (long)f * W_];
        float r = (v - mu) * inv * gam[c * F_ + f] + bet[c * F_ + f];
        long oi = base + (long)f * W_;
        o1[oi] = r;
        if (o2) o2[oi] = r;
        if (px) px[(((long)b * PF_ + f + 1) * PW_ + (w0 + wi) + 1) * 8 + c] = (bf16_t)r;
    }
}

extern "C" void kernel_launch(void* const* d_in, const int* in_sizes, int n_in,
                              void* d_out, int out_size, void* d_ws, size_t ws_size,
                              hipStream_t stream) {
    (void)in_sizes; (void)n_in; (void)out_size; (void)ws_size;
    const float* x        = (const float*)d_in[0];
    const float* prev_qk  = (const float*)d_in[1];
    const float* qconv_w  = (const float*)d_in[2];
    const float* qconv_b  = (const float*)d_in[3];
    const float* q_pw     = (const float*)d_in[4];
    const float* kconv_w  = (const float*)d_in[5];
    const float* kconv_b  = (const float*)d_in[6];
    const float* k_pw     = (const float*)d_in[7];
    const float* vconv_w  = (const float*)d_in[8];
    const float* vconv_b  = (const float*)d_in[9];
    const float* v_pw     = (const float*)d_in[10];
    const float* o_pw     = (const float*)d_in[11];
    const float* o_dw     = (const float*)d_in[12];
    const float* oproj_w  = (const float*)d_in[13];
    const float* oproj_b  = (const float*)d_in[14];
    const float* n1_w     = (const float*)d_in[15];
    const float* n1_b     = (const float*)d_in[16];
    const float* c1_w     = (const float*)d_in[17];
    const float* c1_b     = (const float*)d_in[18];
    const float* c2_w     = (const float*)d_in[19];
    const float* c2_b     = (const float*)d_in[20];
    const float* n2_w     = (const float*)d_in[21];
    const float* n2_b     = (const float*)d_in[22];

    float* out    = (float*)d_out;
    float* qk_out = out + 16777216L;

    // -------- workspace layout (235.2 MB; lifetimes verified vs launch order) --------
    // Phases: A prep | B qkv conv | C mclin q/k/v(+rope) | D attn | E o+odw | F oproj | G ln1 | H ffn
    char* wsb = (char*)d_ws;
    bf16_t* PX8  = (bf16_t*)(wsb + 0L);            // 16,876,032      A..F
    bf16_t* Wq   = (bf16_t*)(wsb + 16876032L);     // 16,777,216      A..C
    bf16_t* Wk   = (bf16_t*)(wsb + 33653248L);     // 16,777,216      A..C
    bf16_t* Wv   = (bf16_t*)(wsb + 50430464L);     // 16,777,216      A..C
    bf16_t* Wo   = (bf16_t*)(wsb + 67207680L);     // 16,777,216      A..E
    bf16_t* QR   = (bf16_t*)(wsb + 83984896L);     // 16,777,216      C..D(qk)
    bf16_t* KR   = (bf16_t*)(wsb + 100762112L);    // 16,777,216      C..D(qk)
    bf16_t* VL   = (bf16_t*)(wsb + 117539328L);    // 16,777,216      C..D(pv)
    bf16_t* QKV  = (bf16_t*)(wsb + 134316544L);    // 50,331,648      B..C
    bf16_t* XT   = (bf16_t*)(wsb + 184648192L);    // 16,777,216      C
    bf16_t* SH   = (bf16_t*)(wsb + 134316544L);    // 67,108,864 over QKV+XT (dead)  D
    bf16_t* AT   = (bf16_t*)(wsb + 201425408L);    // 16,777,216      D..E
    bf16_t* F1b  = (bf16_t*)(wsb + 83984896L);     // 16,777,216 over QR (dead)      E
    bf16_t* PXA2 = (bf16_t*)(wsb + 100762112L);    // 16,875,776 over KR (dead)      E..F
    bf16_t* PRE  = (bf16_t*)(wsb + 134316544L);    // 16,777,216 over SH (dead)      F..H
    float*  HID  = (float*) (wsb + 151093760L);    // 33,554,432 over SH (dead)      G..H
    bf16_t* PXH  = (bf16_t*)(wsb + 218202624L);    // 16,875,776 fresh               E..H
    bf16_t* PXC1 = (bf16_t*)(wsb + 0L);            // 67,502,592 over PX8+Wq..Wo-head (dead) H
    bf16_t* ABQ  = (bf16_t*)(wsb + 235078400L);
    bf16_t* ABO  = (bf16_t*)(wsb + 235078400L + 16384L);
    bf16_t* ABC1 = (bf16_t*)(wsb + 235078400L + 32768L);
    bf16_t* ABC2 = (bf16_t*)(wsb + 235078400L + 49152L);
    float*  BQKV = (float*) (wsb + 235078400L + 65536L);

    const dim3 cvgrid(2, F_, B_);
    const dim3 tgrid(16, 32, 16);
    const dim3 ggrid(4, 8, 16);
    const long BIG = 1 << 30;

    // ---- A: weights -> bf16 ; conv A-matrices ; padded x ----
    cvt_k<<<8192, 256, 0, stream>>>(q_pw, Wq, 2097152);
    cvt_k<<<8192, 256, 0, stream>>>(k_pw, Wk, 2097152);
    cvt_k<<<8192, 256, 0, stream>>>(v_pw, Wv, 2097152);
    cvt_k<<<8192, 256, 0, stream>>>(o_pw, Wo, 2097152);
    aprep_k<<<dim3(18, 4), 256, 0, stream>>>(qconv_w, kconv_w, vconv_w, oproj_w, c1_w, c2_w,
                                             qconv_b, kconv_b, vconv_b,
                                             ABQ, ABO, ABC1, ABC2, BQKV);
    pad_stage_k<<<4121, 256, 0, stream>>>(x, PX8);

    // ---- B: fused q/k/v conv (M=24) ----
    convg_k<8, 1, 2, 0, 0><<<cvgrid, 256, 0, stream>>>(PX8, nullptr, ABQ, BQKV, nullptr, QKV);

    // ---- C: mclin q/k/v (rope fused into q/k epilogues) ----
    tcvt_k<<<tgrid, 256, 0, stream>>>(QKV, XT, 24, 0);
    gemm_mfma_k<2, 1><<<ggrid, 256, 0, stream>>>(Wq, XT, QR, nullptr, 1.f,
        F_, F_, F_, W_, 1048576L, 524288L, 0L, 0L, 1, 0L, 8);

    tcvt_k<<<tgrid, 256, 0, stream>>>(QKV, XT, 24, 8);
    gemm_mfma_k<2, 1><<<ggrid, 256, 0, stream>>>(Wk, XT, KR, nullptr, 1.f,
        F_, F_, F_, W_, 1048576L, 524288L, 0L, 0L, 1, 0L, 8);

    tcvt_k<<<tgrid, 256, 0, stream>>>(QKV, XT, 24, 16);
    gemm_mfma_k<0, 1><<<ggrid, 256, 0, stream>>>(Wv, XT, VL, nullptr, 1.f,
        F_, F_, F_, W_, 1048576L, 524288L, 524288L, 0L, 1, 0L, 8);

    // ---- D: attention ----
    gemm_mfma_k<1, 0><<<dim3(4, 4, 128), 256, 0, stream>>>(QR, KR, qk_out, prev_qk,
        0.03125f, HD_, HD_, HD_, W_, 65536L, 65536L, 262144L, 0L, 1, 262144L, (int)BIG);
    softmax_k<<<16384, 256, 0, stream>>>(qk_out, SH);
    gemm_mfma_k<0, 1><<<dim3(1, 4, 128), 256, 0, stream>>>(SH, VL, AT, nullptr, 1.f,
        W_, W_, W_, F_, 262144L, 65536L, 524288L, 128L, 8, 0L, (int)BIG);

    // ---- E: o linear (bf16 out) + depthwise mix ----
    gemm_mfma_k<0, 1><<<ggrid, 256, 0, stream>>>(Wo, AT, F1b, nullptr, 1.f,
        F_, F_, F_, W_, 1048576L, 524288L, 524288L, 0L, 1, 0L, 8);
    odw_k<<<4096, 256, 0, stream>>>(F1b, o_dw, PXA2);
    borderz8_k<<<25, 256, 0, stream>>>(PXA2, PXH);

    // ---- F: oproj conv (x ++ a2) + x residual -> pre1 (bf16) ----
    convg_k<8, 2, 1, 1, 1><<<cvgrid, 256, 0, stream>>>(PX8, PXA2, ABO, oproj_b, x, PRE);
    borderz32_k<<<25, 256, 0, stream>>>(PXC1);

    // ---- G: hid = mcln(pre1) -> HID fp32 + PXH channels-last bf16 ----
    mcln_k<bf16_t><<<dim3(16, 8, 2), 256, 0, stream>>>(PRE, n1_w, n1_b, HID, nullptr, PXH);

    // ---- H: ffn ----
    convg_k<8, 1, 2, 0, 2><<<cvgrid, 256, 0, stream>>>(PXH, nullptr, ABC1, c1_b, nullptr, PXC1);
    convg_k<32, 3, 1, 0, 1><<<cvgrid, 256, 0, stream>>>(PXC1, nullptr, ABC2, c2_b, HID, PRE);
    mcln_k<bf16_t><<<dim3(16, 8, 2), 256, 0, stream>>>(PRE, n2_w, n2_b, out, out + 8388608L, nullptr);
}